// Round 1
// baseline (835.767 us; speedup 1.0000x reference)
//
#include <hip/hip_runtime.h>
#include <hip/hip_bf16.h>
#include <cstddef>

#define NNODES 40000
#define NEDGES 640000
#define NETOT  (NNODES + NEDGES)

// ---------------- wave helpers ----------------
__device__ inline float wave_sum(float v) {
#pragma unroll
    for (int o = 32; o > 0; o >>= 1) v += __shfl_xor(v, o);
    return v;
}
__device__ inline float wave_max(float v) {
#pragma unroll
    for (int o = 32; o > 0; o >>= 1) v = fmaxf(v, __shfl_xor(v, o));
    return v;
}

// ---------------- CSR build ----------------
__global__ void count_kernel(const int* __restrict__ ei, int* __restrict__ deg) {
    int idx = blockIdx.x * blockDim.x + threadIdx.x;
    if (idx >= NETOT) return;
    int dst = (idx < NEDGES) ? ei[NEDGES + idx] : (idx - NEDGES);
    atomicAdd(&deg[dst], 1);
}

__global__ void scan_excl_kernel(const int* __restrict__ deg, int* __restrict__ offs, int n) {
    __shared__ int tmp[256];
    __shared__ int carry;
    if (threadIdx.x == 0) carry = 0;
    __syncthreads();
    for (int base = 0; base < n; base += 256) {
        int i = base + threadIdx.x;
        int v = (i < n) ? deg[i] : 0;
        tmp[threadIdx.x] = v;
        __syncthreads();
        int acc = v;
#pragma unroll
        for (int off = 1; off < 256; off <<= 1) {
            int t = (threadIdx.x >= off) ? tmp[threadIdx.x - off] : 0;
            __syncthreads();
            acc += t;
            tmp[threadIdx.x] = acc;
            __syncthreads();
        }
        int exclusive = acc - v;
        int c = carry;
        if (i < n) offs[i] = c + exclusive;
        __syncthreads();
        if (threadIdx.x == 255) carry = c + tmp[255];
        __syncthreads();
    }
    if (threadIdx.x == 0) offs[n] = carry;
}

__global__ void initcur_kernel(const int* __restrict__ offs, int* __restrict__ cursor, int n) {
    int i = blockIdx.x * blockDim.x + threadIdx.x;
    if (i < n) cursor[i] = offs[i];
}

__global__ void scatter_kernel(const int* __restrict__ ei, int* __restrict__ cursor,
                               int* __restrict__ srcs) {
    int idx = blockIdx.x * blockDim.x + threadIdx.x;
    if (idx >= NETOT) return;
    int src, dst;
    if (idx < NEDGES) { src = ei[idx]; dst = ei[NEDGES + idx]; }
    else              { src = idx - NEDGES; dst = src; }
    int p = atomicAdd(&cursor[dst], 1);
    srcs[p] = src;
}

// ---------------- fp32 tiled GEMM: C[M,N] = A[M,K] @ B[N,K]^T (+epilogue) ----------------
// Requires M%64==0, N%64==0, K%16==0. grid = (M/64, N/64), block = 256.
template <bool BN, bool RELU>
__global__ void gemm_kernel(const float* __restrict__ A, const float* __restrict__ B,
                            float* __restrict__ C, int M, int Nn, int K,
                            const float* __restrict__ bias,
                            const float* __restrict__ bng, const float* __restrict__ bnb) {
    __shared__ float As[16][68];
    __shared__ float Bs[16][68];
    int m0 = blockIdx.x * 64;
    int n0 = blockIdx.y * 64;
    int tx = threadIdx.x & 15;      // 4-col microtile index
    int ty = threadIdx.x >> 4;      // 4-row microtile index
    int lm = threadIdx.x >> 2;      // 0..63 row within tile for loads
    int lk = (threadIdx.x & 3) * 4; // 0,4,8,12 k-offset for loads
    float acc[4][4] = {};
    for (int k0 = 0; k0 < K; k0 += 16) {
        float4 av = *(const float4*)(A + (size_t)(m0 + lm) * K + k0 + lk);
        float4 bv = *(const float4*)(B + (size_t)(n0 + lm) * K + k0 + lk);
        As[lk + 0][lm] = av.x; As[lk + 1][lm] = av.y; As[lk + 2][lm] = av.z; As[lk + 3][lm] = av.w;
        Bs[lk + 0][lm] = bv.x; Bs[lk + 1][lm] = bv.y; Bs[lk + 2][lm] = bv.z; Bs[lk + 3][lm] = bv.w;
        __syncthreads();
#pragma unroll
        for (int k = 0; k < 16; k++) {
            float4 a4 = *(const float4*)&As[k][ty * 4];
            float4 b4 = *(const float4*)&Bs[k][tx * 4];
            float aa[4] = {a4.x, a4.y, a4.z, a4.w};
            float bb[4] = {b4.x, b4.y, b4.z, b4.w};
#pragma unroll
            for (int i = 0; i < 4; i++)
#pragma unroll
                for (int j = 0; j < 4; j++) acc[i][j] += aa[i] * bb[j];
        }
        __syncthreads();
    }
#pragma unroll
    for (int i = 0; i < 4; i++) {
        int row = m0 + ty * 4 + i;
        float vv[4];
#pragma unroll
        for (int j = 0; j < 4; j++) {
            int col = n0 + tx * 4 + j;
            float v = acc[i][j];
            if (bias) v += bias[col];
            if (BN) v = v * (bng[col] * rsqrtf(1.0f + 1e-5f)) + bnb[col];
            if (RELU) v = v > 0.f ? v : 0.f;
            vv[j] = v;
        }
        *(float4*)(C + (size_t)row * Nn + n0 + tx * 4) = make_float4(vv[0], vv[1], vv[2], vv[3]);
    }
}

// ---------------- GAT attention scores: es/ed per node per head ----------------
template <int H, int C>
__global__ void gat_scores_kernel(const float* __restrict__ hmat,
                                  const float* __restrict__ as, const float* __restrict__ ad,
                                  float* __restrict__ es, float* __restrict__ ed, int n) {
    constexpr int HC = H * C;
    int wid = (blockIdx.x * blockDim.x + threadIdx.x) >> 6;
    int lane = threadIdx.x & 63;
    if (wid >= n) return;
    const float* hp = hmat + (size_t)wid * HC;
    float ps[H], pd[H];
#pragma unroll
    for (int hh = 0; hh < H; hh++) { ps[hh] = 0.f; pd[hh] = 0.f; }
#pragma unroll
    for (int f0 = 0; f0 < HC; f0 += 64) {
        const int hh = f0 / C;   // compile-time constant per unrolled iteration (C is 64 or 128)
        int f = f0 + lane;
        float hv = hp[f];
        ps[hh] += hv * as[f];
        pd[hh] += hv * ad[f];
    }
#pragma unroll
    for (int hh = 0; hh < H; hh++) {
        float s = wave_sum(ps[hh]);
        float d = wave_sum(pd[hh]);
        if (lane == 0) {
            es[(size_t)wid * H + hh] = s;
            ed[(size_t)wid * H + hh] = d;
        }
    }
}

// ---------------- GAT aggregation (segment softmax + weighted sum), one wave/node ----------------
template <int H, int C, bool LNRELU>
__global__ void gat_agg_kernel(const float* __restrict__ hmat,
                               const float* __restrict__ es, const float* __restrict__ ed,
                               const int* __restrict__ offs, const int* __restrict__ srcs,
                               const float* __restrict__ bias,
                               const float* __restrict__ lng, const float* __restrict__ lnb,
                               float* __restrict__ out, int n) {
    constexpr int HC = H * C;
    constexpr int VPT = HC / 64;
    int wid = (blockIdx.x * blockDim.x + threadIdx.x) >> 6;
    int lane = threadIdx.x & 63;
    if (wid >= n) return;
    int start = offs[wid], end = offs[wid + 1];

    float edi[H];
#pragma unroll
    for (int hh = 0; hh < H; hh++) edi[hh] = ed[(size_t)wid * H + hh];

    // pass 1: segment max per head
    float m[H];
#pragma unroll
    for (int hh = 0; hh < H; hh++) m[hh] = -1e30f;
    for (int e = start + lane; e < end; e += 64) {
        int s = srcs[e];
#pragma unroll
        for (int hh = 0; hh < H; hh++) {
            float v = es[(size_t)s * H + hh] + edi[hh];
            v = v > 0.f ? v : 0.2f * v;
            m[hh] = fmaxf(m[hh], v);
        }
    }
#pragma unroll
    for (int hh = 0; hh < H; hh++) m[hh] = wave_max(m[hh]);

    // pass 2: exp-sum per head
    float den[H];
#pragma unroll
    for (int hh = 0; hh < H; hh++) den[hh] = 0.f;
    for (int e = start + lane; e < end; e += 64) {
        int s = srcs[e];
#pragma unroll
        for (int hh = 0; hh < H; hh++) {
            float v = es[(size_t)s * H + hh] + edi[hh];
            v = v > 0.f ? v : 0.2f * v;
            den[hh] += __expf(v - m[hh]);
        }
    }
#pragma unroll
    for (int hh = 0; hh < H; hh++) den[hh] = wave_sum(den[hh]) + 1e-16f;

    // pass 3: weighted accumulate; each lane owns VPT consecutive features
    const int myhead = (lane * VPT) / C;
    float mh = m[myhead];
    float invden = 1.f / den[myhead];
    float edh = edi[myhead];
    float acc[VPT];
#pragma unroll
    for (int j = 0; j < VPT; j++) acc[j] = 0.f;

    for (int e = start; e < end; e++) {
        int s = srcs[e];
        float v = es[(size_t)s * H + myhead] + edh;
        v = v > 0.f ? v : 0.2f * v;
        float w = __expf(v - mh) * invden;
        const float* hp = hmat + (size_t)s * HC + lane * VPT;
        if constexpr (VPT == 4) {
            float4 hv = *(const float4*)hp;
            acc[0] += w * hv.x; acc[1] += w * hv.y; acc[2] += w * hv.z; acc[3] += w * hv.w;
        } else {
            float2 hv = *(const float2*)hp;
            acc[0] += w * hv.x; acc[1] += w * hv.y;
        }
    }

    int fbase = lane * VPT;
    float y[VPT];
#pragma unroll
    for (int j = 0; j < VPT; j++) y[j] = acc[j] + bias[fbase + j];

    if constexpr (LNRELU) {
        float s1 = 0.f, s2 = 0.f;
#pragma unroll
        for (int j = 0; j < VPT; j++) { s1 += y[j]; s2 += y[j] * y[j]; }
        s1 = wave_sum(s1);
        s2 = wave_sum(s2);
        float mu = s1 / (float)HC;
        float var = s2 / (float)HC - mu * mu;
        float rstd = rsqrtf(var + 1e-5f);
#pragma unroll
        for (int j = 0; j < VPT; j++) {
            float v = (y[j] - mu) * rstd * lng[fbase + j] + lnb[fbase + j];
            y[j] = v > 0.f ? v : 0.f;
        }
    }
    float* op = out + (size_t)wid * HC + fbase;
    if constexpr (VPT == 4) *(float4*)op = make_float4(y[0], y[1], y[2], y[3]);
    else                    *(float2*)op = make_float2(y[0], y[1]);
}

// ---------------- PointNet layer 1 (K=3) + BN + ReLU ----------------
__global__ void pn1_kernel(const float* __restrict__ pos, const float* __restrict__ pw1,
                           const float* __restrict__ pb1, const float* __restrict__ g,
                           const float* __restrict__ b, float* __restrict__ out, int n) {
    int idx = blockIdx.x * blockDim.x + threadIdx.x;
    if (idx >= n * 64) return;
    int node = idx >> 6, o = idx & 63;
    float p0 = pos[node * 3 + 0], p1 = pos[node * 3 + 1], p2 = pos[node * 3 + 2];
    float v = p0 * pw1[o * 3 + 0] + p1 * pw1[o * 3 + 1] + p2 * pw1[o * 3 + 2] + pb1[o];
    v = v * (g[o] * rsqrtf(1.0f + 1e-5f)) + b[o];
    out[idx] = v > 0.f ? v : 0.f;
}

// ---------------- concat [x3 | pos_features] -> combined [N,256] ----------------
__global__ void concat_kernel(const float* __restrict__ x3, const float* __restrict__ pf,
                              float* __restrict__ comb, int n) {
    int idx = blockIdx.x * blockDim.x + threadIdx.x;  // over n*64 float4s
    if (idx >= n * 64) return;
    int node = idx >> 6, c4 = idx & 63;
    float4 v = (c4 < 32) ? ((const float4*)x3)[(size_t)node * 32 + c4]
                         : ((const float4*)pf)[(size_t)node * 32 + (c4 - 32)];
    ((float4*)comb)[idx] = v;
}

extern "C" void kernel_launch(void* const* d_in, const int* in_sizes, int n_in,
                              void* d_out, int out_size, void* d_ws, size_t ws_size,
                              hipStream_t stream) {
    const float* x    = (const float*)d_in[0];
    const int*   ei   = (const int*)d_in[1];
    const float* pos  = (const float*)d_in[2];
    const float* W1   = (const float*)d_in[3];
    const float* as1  = (const float*)d_in[4];
    const float* ad1  = (const float*)d_in[5];
    const float* bg1  = (const float*)d_in[6];
    const float* ln1g = (const float*)d_in[7];
    const float* ln1b = (const float*)d_in[8];
    const float* W2   = (const float*)d_in[9];
    const float* as2  = (const float*)d_in[10];
    const float* ad2  = (const float*)d_in[11];
    const float* bg2  = (const float*)d_in[12];
    const float* ln2g = (const float*)d_in[13];
    const float* ln2b = (const float*)d_in[14];
    const float* W3   = (const float*)d_in[15];
    const float* as3  = (const float*)d_in[16];
    const float* ad3  = (const float*)d_in[17];
    const float* bg3  = (const float*)d_in[18];
    const float* pw1  = (const float*)d_in[19];
    const float* pb1  = (const float*)d_in[20];
    const float* bn1g = (const float*)d_in[21];
    const float* bn1b = (const float*)d_in[22];
    const float* pw2  = (const float*)d_in[23];
    const float* pb2  = (const float*)d_in[24];
    const float* bn2g = (const float*)d_in[25];
    const float* bn2b = (const float*)d_in[26];
    const float* pw3  = (const float*)d_in[27];
    const float* pb3  = (const float*)d_in[28];
    const float* fw   = (const float*)d_in[29];
    const float* fb   = (const float*)d_in[30];

    const int N = NNODES;
    float* out = (float*)d_out;                    // [N,128]
    float* x3  = out + (size_t)N * 128;            // [N,128]
    float* pf  = out + (size_t)2 * N * 128;        // [N,128]

    char* ws = (char*)d_ws;
    size_t off = 0;
    auto alloc = [&](size_t bytes) -> void* {
        void* p = ws + off;
        off += (bytes + 255) / 256 * 256;
        return p;
    };
    int*   offs   = (int*)alloc((size_t)(N + 1) * 4);
    int*   cursor = (int*)alloc((size_t)N * 4);          // doubles as degree array
    int*   srcs   = (int*)alloc((size_t)NETOT * 4);
    float* esb    = (float*)alloc((size_t)N * 4 * 4);
    float* edb    = (float*)alloc((size_t)N * 4 * 4);
    float* hbuf   = (float*)alloc((size_t)N * 256 * 4);  // h per layer; later p1/p2
    float* xbuf   = (float*)alloc((size_t)N * 256 * 4);  // x1; then x2; then combined

    // ---- CSR build (by dst, incl. self-loops) ----
    hipMemsetAsync(cursor, 0, (size_t)N * 4, stream);
    count_kernel<<<(NETOT + 255) / 256, 256, 0, stream>>>(ei, cursor);
    scan_excl_kernel<<<1, 256, 0, stream>>>(cursor, offs, N);
    initcur_kernel<<<(N + 255) / 256, 256, 0, stream>>>(offs, cursor, N);
    scatter_kernel<<<(NETOT + 255) / 256, 256, 0, stream>>>(ei, cursor, srcs);

    const int NW = N / 4;  // blocks for one-wave-per-node kernels (256 thr = 4 waves)

    // ---- GAT layer 1: h1 = x@W1^T [N,256]; agg + bias + LN + ReLU -> x1 ----
    gemm_kernel<false, false><<<dim3(N / 64, 4), 256, 0, stream>>>(
        x, W1, hbuf, N, 256, 64, nullptr, nullptr, nullptr);
    gat_scores_kernel<4, 64><<<NW, 256, 0, stream>>>(hbuf, as1, ad1, esb, edb, N);
    gat_agg_kernel<4, 64, true><<<NW, 256, 0, stream>>>(
        hbuf, esb, edb, offs, srcs, bg1, ln1g, ln1b, xbuf, N);

    // ---- GAT layer 2: h2 = x1@W2^T [N,128]; agg -> x2 (reuse xbuf after h2 GEMM) ----
    gemm_kernel<false, false><<<dim3(N / 64, 2), 256, 0, stream>>>(
        xbuf, W2, hbuf, N, 128, 256, nullptr, nullptr, nullptr);
    gat_scores_kernel<2, 64><<<NW, 256, 0, stream>>>(hbuf, as2, ad2, esb, edb, N);
    gat_agg_kernel<2, 64, true><<<NW, 256, 0, stream>>>(
        hbuf, esb, edb, offs, srcs, bg2, ln2g, ln2b, xbuf, N);

    // ---- GAT layer 3: h3 = x2@W3^T [N,128]; agg + bias -> x3 (no LN/ReLU) ----
    gemm_kernel<false, false><<<dim3(N / 64, 2), 256, 0, stream>>>(
        xbuf, W3, hbuf, N, 128, 128, nullptr, nullptr, nullptr);
    gat_scores_kernel<1, 128><<<NW, 256, 0, stream>>>(hbuf, as3, ad3, esb, edb, N);
    gat_agg_kernel<1, 128, false><<<NW, 256, 0, stream>>>(
        hbuf, esb, edb, offs, srcs, bg3, nullptr, nullptr, x3, N);

    // ---- PointNet (reuse hbuf: p1 = hbuf[N,64], p2 = hbuf+N*64 [N,128]) ----
    float* p1 = hbuf;
    float* p2 = hbuf + (size_t)N * 64;
    pn1_kernel<<<(N * 64 + 255) / 256, 256, 0, stream>>>(pos, pw1, pb1, bn1g, bn1b, p1, N);
    gemm_kernel<true, true><<<dim3(N / 64, 2), 256, 0, stream>>>(
        p1, pw2, p2, N, 128, 64, pb2, bn2g, bn2b);
    gemm_kernel<false, false><<<dim3(N / 64, 2), 256, 0, stream>>>(
        p2, pw3, pf, N, 128, 128, pb3, nullptr, nullptr);

    // ---- fusion: combined = [x3|pf] [N,256]; out = combined@fw^T + fb ----
    concat_kernel<<<(N * 64 + 255) / 256, 256, 0, stream>>>(x3, pf, xbuf, N);
    gemm_kernel<false, false><<<dim3(N / 64, 2), 256, 0, stream>>>(
        xbuf, fw, out, N, 128, 256, fb, nullptr, nullptr);
}

// Round 2
// 692.116 us; speedup vs baseline: 1.2076x; 1.2076x over previous
//
#include <hip/hip_runtime.h>
#include <hip/hip_bf16.h>
#include <cstddef>

#define NNODES 40000
#define NEDGES 640000
#define NETOT  (NNODES + NEDGES)
#define NSCANB ((NNODES + 255) / 256)   // 157 scan blocks

// ---------------- wave helpers ----------------
__device__ inline float wave_sum(float v) {
#pragma unroll
    for (int o = 32; o > 0; o >>= 1) v += __shfl_xor(v, o);
    return v;
}
__device__ inline float wave_max(float v) {
#pragma unroll
    for (int o = 32; o > 0; o >>= 1) v = fmaxf(v, __shfl_xor(v, o));
    return v;
}

// ---------------- CSR build ----------------
__global__ void count_kernel(const int* __restrict__ ei, int* __restrict__ deg) {
    int idx = blockIdx.x * blockDim.x + threadIdx.x;
    if (idx >= NETOT) return;
    int dst = (idx < NEDGES) ? ei[NEDGES + idx] : (idx - NEDGES);
    atomicAdd(&deg[dst], 1);
}

// stage 1: per-block exclusive scan of deg, emit block sums. grid=NSCANB, block=256
__global__ void scan1_kernel(const int* __restrict__ deg, int* __restrict__ offs,
                             int* __restrict__ bsum, int n) {
    __shared__ int tmp[256];
    int i = blockIdx.x * 256 + threadIdx.x;
    int v = (i < n) ? deg[i] : 0;
    tmp[threadIdx.x] = v;
    __syncthreads();
    int acc = v;
#pragma unroll
    for (int off = 1; off < 256; off <<= 1) {
        int t = (threadIdx.x >= off) ? tmp[threadIdx.x - off] : 0;
        __syncthreads();
        acc += t;
        tmp[threadIdx.x] = acc;
        __syncthreads();
    }
    if (i < n) offs[i] = acc - v;              // block-local exclusive
    if (threadIdx.x == 255) bsum[blockIdx.x] = acc;
}

// stage 2: single block exclusive-scans the block sums in place (nb <= 256)
__global__ void scan2_kernel(int* __restrict__ bsum, int nb) {
    __shared__ int tmp[256];
    int v = (threadIdx.x < nb) ? bsum[threadIdx.x] : 0;
    tmp[threadIdx.x] = v;
    __syncthreads();
    int acc = v;
#pragma unroll
    for (int off = 1; off < 256; off <<= 1) {
        int t = (threadIdx.x >= off) ? tmp[threadIdx.x - off] : 0;
        __syncthreads();
        acc += t;
        tmp[threadIdx.x] = acc;
        __syncthreads();
    }
    if (threadIdx.x < nb) bsum[threadIdx.x] = acc - v;   // exclusive
}

// stage 3: add block offsets; init cursor; write offs[n] (= NETOT statically)
__global__ void scan3_kernel(int* __restrict__ offs, const int* __restrict__ bsum,
                             int* __restrict__ cursor, int n) {
    int i = blockIdx.x * 256 + threadIdx.x;
    if (i < n) {
        int o = offs[i] + bsum[blockIdx.x];
        offs[i] = o;
        cursor[i] = o;
    }
    if (i == 0) offs[n] = NETOT;
}

__global__ void scatter_kernel(const int* __restrict__ ei, int* __restrict__ cursor,
                               int* __restrict__ srcs) {
    int idx = blockIdx.x * blockDim.x + threadIdx.x;
    if (idx >= NETOT) return;
    int src, dst;
    if (idx < NEDGES) { src = ei[idx]; dst = ei[NEDGES + idx]; }
    else              { src = idx - NEDGES; dst = src; }
    int p = atomicAdd(&cursor[dst], 1);
    srcs[p] = src;
}

// ---------------- fp32 tiled GEMM: C[M,N] = A[M,K] @ B[N,K]^T (+epilogue) ----------------
// Requires M%64==0, N%64==0, K%16==0. grid = (M/64, N/64), block = 256.
template <bool BN, bool RELU>
__global__ void gemm_kernel(const float* __restrict__ A, const float* __restrict__ B,
                            float* __restrict__ C, int M, int Nn, int K,
                            const float* __restrict__ bias,
                            const float* __restrict__ bng, const float* __restrict__ bnb) {
    __shared__ float As[16][68];
    __shared__ float Bs[16][68];
    int m0 = blockIdx.x * 64;
    int n0 = blockIdx.y * 64;
    int tx = threadIdx.x & 15;      // 4-col microtile index
    int ty = threadIdx.x >> 4;      // 4-row microtile index
    int lm = threadIdx.x >> 2;      // 0..63 row within tile for loads
    int lk = (threadIdx.x & 3) * 4; // 0,4,8,12 k-offset for loads
    float acc[4][4] = {};
    for (int k0 = 0; k0 < K; k0 += 16) {
        float4 av = *(const float4*)(A + (size_t)(m0 + lm) * K + k0 + lk);
        float4 bv = *(const float4*)(B + (size_t)(n0 + lm) * K + k0 + lk);
        As[lk + 0][lm] = av.x; As[lk + 1][lm] = av.y; As[lk + 2][lm] = av.z; As[lk + 3][lm] = av.w;
        Bs[lk + 0][lm] = bv.x; Bs[lk + 1][lm] = bv.y; Bs[lk + 2][lm] = bv.z; Bs[lk + 3][lm] = bv.w;
        __syncthreads();
#pragma unroll
        for (int k = 0; k < 16; k++) {
            float4 a4 = *(const float4*)&As[k][ty * 4];
            float4 b4 = *(const float4*)&Bs[k][tx * 4];
            float aa[4] = {a4.x, a4.y, a4.z, a4.w};
            float bb[4] = {b4.x, b4.y, b4.z, b4.w};
#pragma unroll
            for (int i = 0; i < 4; i++)
#pragma unroll
                for (int j = 0; j < 4; j++) acc[i][j] += aa[i] * bb[j];
        }
        __syncthreads();
    }
#pragma unroll
    for (int i = 0; i < 4; i++) {
        int row = m0 + ty * 4 + i;
        float vv[4];
#pragma unroll
        for (int j = 0; j < 4; j++) {
            int col = n0 + tx * 4 + j;
            float v = acc[i][j];
            if (bias) v += bias[col];
            if (BN) v = v * (bng[col] * rsqrtf(1.0f + 1e-5f)) + bnb[col];
            if (RELU) v = v > 0.f ? v : 0.f;
            vv[j] = v;
        }
        *(float4*)(C + (size_t)row * Nn + n0 + tx * 4) = make_float4(vv[0], vv[1], vv[2], vv[3]);
    }
}

// ---------------- GAT attention scores: es/ed per node per head ----------------
template <int H, int C>
__global__ void gat_scores_kernel(const float* __restrict__ hmat,
                                  const float* __restrict__ as, const float* __restrict__ ad,
                                  float* __restrict__ es, float* __restrict__ ed, int n) {
    constexpr int HC = H * C;
    int wid = (blockIdx.x * blockDim.x + threadIdx.x) >> 6;
    int lane = threadIdx.x & 63;
    if (wid >= n) return;
    const float* hp = hmat + (size_t)wid * HC;
    float ps[H], pd[H];
#pragma unroll
    for (int hh = 0; hh < H; hh++) { ps[hh] = 0.f; pd[hh] = 0.f; }
#pragma unroll
    for (int f0 = 0; f0 < HC; f0 += 64) {
        const int hh = f0 / C;   // compile-time constant per unrolled iteration
        int f = f0 + lane;
        float hv = hp[f];
        ps[hh] += hv * as[f];
        pd[hh] += hv * ad[f];
    }
#pragma unroll
    for (int hh = 0; hh < H; hh++) {
        float s = wave_sum(ps[hh]);
        float d = wave_sum(pd[hh]);
        if (lane == 0) {
            es[(size_t)wid * H + hh] = s;
            ed[(size_t)wid * H + hh] = d;
        }
    }
}

// ---------------- GAT aggregation (segment softmax + weighted sum), one wave/node ----------------
template <int H, int C, bool LNRELU>
__global__ void gat_agg_kernel(const float* __restrict__ hmat,
                               const float* __restrict__ es, const float* __restrict__ ed,
                               const int* __restrict__ offs, const int* __restrict__ srcs,
                               const float* __restrict__ bias,
                               const float* __restrict__ lng, const float* __restrict__ lnb,
                               float* __restrict__ out, int n) {
    constexpr int HC = H * C;
    constexpr int VPT = HC / 64;
    int wid = (blockIdx.x * blockDim.x + threadIdx.x) >> 6;
    int lane = threadIdx.x & 63;
    if (wid >= n) return;
    int start = offs[wid], end = offs[wid + 1];

    float edi[H];
#pragma unroll
    for (int hh = 0; hh < H; hh++) edi[hh] = ed[(size_t)wid * H + hh];

    // pass 1: segment max per head
    float m[H];
#pragma unroll
    for (int hh = 0; hh < H; hh++) m[hh] = -1e30f;
    for (int e = start + lane; e < end; e += 64) {
        int s = srcs[e];
#pragma unroll
        for (int hh = 0; hh < H; hh++) {
            float v = es[(size_t)s * H + hh] + edi[hh];
            v = v > 0.f ? v : 0.2f * v;
            m[hh] = fmaxf(m[hh], v);
        }
    }
#pragma unroll
    for (int hh = 0; hh < H; hh++) m[hh] = wave_max(m[hh]);

    // pass 2: exp-sum per head
    float den[H];
#pragma unroll
    for (int hh = 0; hh < H; hh++) den[hh] = 0.f;
    for (int e = start + lane; e < end; e += 64) {
        int s = srcs[e];
#pragma unroll
        for (int hh = 0; hh < H; hh++) {
            float v = es[(size_t)s * H + hh] + edi[hh];
            v = v > 0.f ? v : 0.2f * v;
            den[hh] += __expf(v - m[hh]);
        }
    }
#pragma unroll
    for (int hh = 0; hh < H; hh++) den[hh] = wave_sum(den[hh]) + 1e-16f;

    // pass 3: weighted accumulate; each lane owns VPT consecutive features
    const int myhead = (lane * VPT) / C;
    float mh = m[myhead];
    float invden = 1.f / den[myhead];
    float edh = edi[myhead];
    float acc[VPT];
#pragma unroll
    for (int j = 0; j < VPT; j++) acc[j] = 0.f;

    for (int e = start; e < end; e++) {
        int s = srcs[e];
        float v = es[(size_t)s * H + myhead] + edh;
        v = v > 0.f ? v : 0.2f * v;
        float w = __expf(v - mh) * invden;
        const float* hp = hmat + (size_t)s * HC + lane * VPT;
        if constexpr (VPT == 4) {
            float4 hv = *(const float4*)hp;
            acc[0] += w * hv.x; acc[1] += w * hv.y; acc[2] += w * hv.z; acc[3] += w * hv.w;
        } else {
            float2 hv = *(const float2*)hp;
            acc[0] += w * hv.x; acc[1] += w * hv.y;
        }
    }

    int fbase = lane * VPT;
    float y[VPT];
#pragma unroll
    for (int j = 0; j < VPT; j++) y[j] = acc[j] + bias[fbase + j];

    if constexpr (LNRELU) {
        float s1 = 0.f, s2 = 0.f;
#pragma unroll
        for (int j = 0; j < VPT; j++) { s1 += y[j]; s2 += y[j] * y[j]; }
        s1 = wave_sum(s1);
        s2 = wave_sum(s2);
        float mu = s1 / (float)HC;
        float var = s2 / (float)HC - mu * mu;
        float rstd = rsqrtf(var + 1e-5f);
#pragma unroll
        for (int j = 0; j < VPT; j++) {
            float v = (y[j] - mu) * rstd * lng[fbase + j] + lnb[fbase + j];
            y[j] = v > 0.f ? v : 0.f;
        }
    }
    float* op = out + (size_t)wid * HC + fbase;
    if constexpr (VPT == 4) *(float4*)op = make_float4(y[0], y[1], y[2], y[3]);
    else                    *(float2*)op = make_float2(y[0], y[1]);
}

// ---------------- PointNet layer 1 (K=3) + BN + ReLU ----------------
__global__ void pn1_kernel(const float* __restrict__ pos, const float* __restrict__ pw1,
                           const float* __restrict__ pb1, const float* __restrict__ g,
                           const float* __restrict__ b, float* __restrict__ out, int n) {
    int idx = blockIdx.x * blockDim.x + threadIdx.x;
    if (idx >= n * 64) return;
    int node = idx >> 6, o = idx & 63;
    float p0 = pos[node * 3 + 0], p1 = pos[node * 3 + 1], p2 = pos[node * 3 + 2];
    float v = p0 * pw1[o * 3 + 0] + p1 * pw1[o * 3 + 1] + p2 * pw1[o * 3 + 2] + pb1[o];
    v = v * (g[o] * rsqrtf(1.0f + 1e-5f)) + b[o];
    out[idx] = v > 0.f ? v : 0.f;
}

// ---------------- concat [x3 | pos_features] -> combined [N,256] ----------------
__global__ void concat_kernel(const float* __restrict__ x3, const float* __restrict__ pf,
                              float* __restrict__ comb, int n) {
    int idx = blockIdx.x * blockDim.x + threadIdx.x;  // over n*64 float4s
    if (idx >= n * 64) return;
    int node = idx >> 6, c4 = idx & 63;
    float4 v = (c4 < 32) ? ((const float4*)x3)[(size_t)node * 32 + c4]
                         : ((const float4*)pf)[(size_t)node * 32 + (c4 - 32)];
    ((float4*)comb)[idx] = v;
}

extern "C" void kernel_launch(void* const* d_in, const int* in_sizes, int n_in,
                              void* d_out, int out_size, void* d_ws, size_t ws_size,
                              hipStream_t stream) {
    const float* x    = (const float*)d_in[0];
    const int*   ei   = (const int*)d_in[1];
    const float* pos  = (const float*)d_in[2];
    const float* W1   = (const float*)d_in[3];
    const float* as1  = (const float*)d_in[4];
    const float* ad1  = (const float*)d_in[5];
    const float* bg1  = (const float*)d_in[6];
    const float* ln1g = (const float*)d_in[7];
    const float* ln1b = (const float*)d_in[8];
    const float* W2   = (const float*)d_in[9];
    const float* as2  = (const float*)d_in[10];
    const float* ad2  = (const float*)d_in[11];
    const float* bg2  = (const float*)d_in[12];
    const float* ln2g = (const float*)d_in[13];
    const float* ln2b = (const float*)d_in[14];
    const float* W3   = (const float*)d_in[15];
    const float* as3  = (const float*)d_in[16];
    const float* ad3  = (const float*)d_in[17];
    const float* bg3  = (const float*)d_in[18];
    const float* pw1  = (const float*)d_in[19];
    const float* pb1  = (const float*)d_in[20];
    const float* bn1g = (const float*)d_in[21];
    const float* bn1b = (const float*)d_in[22];
    const float* pw2  = (const float*)d_in[23];
    const float* pb2  = (const float*)d_in[24];
    const float* bn2g = (const float*)d_in[25];
    const float* bn2b = (const float*)d_in[26];
    const float* pw3  = (const float*)d_in[27];
    const float* pb3  = (const float*)d_in[28];
    const float* fw   = (const float*)d_in[29];
    const float* fb   = (const float*)d_in[30];

    const int N = NNODES;
    float* out = (float*)d_out;                    // [N,128]
    float* x3  = out + (size_t)N * 128;            // [N,128]
    float* pf  = out + (size_t)2 * N * 128;        // [N,128]

    char* ws = (char*)d_ws;
    size_t off = 0;
    auto alloc = [&](size_t bytes) -> void* {
        void* p = ws + off;
        off += (bytes + 255) / 256 * 256;
        return p;
    };
    int*   offs   = (int*)alloc((size_t)(N + 1) * 4);
    int*   cursor = (int*)alloc((size_t)N * 4);          // doubles as degree array
    int*   bsum   = (int*)alloc((size_t)NSCANB * 4);
    int*   srcs   = (int*)alloc((size_t)NETOT * 4);
    float* esb    = (float*)alloc((size_t)N * 4 * 4);
    float* edb    = (float*)alloc((size_t)N * 4 * 4);
    float* hbuf   = (float*)alloc((size_t)N * 256 * 4);  // h per layer; later p1/p2
    float* xbuf   = (float*)alloc((size_t)N * 256 * 4);  // x1; then x2; then combined

    // ---- CSR build (by dst, incl. self-loops), parallel 3-stage scan ----
    hipMemsetAsync(cursor, 0, (size_t)N * 4, stream);
    count_kernel<<<(NETOT + 255) / 256, 256, 0, stream>>>(ei, cursor);
    scan1_kernel<<<NSCANB, 256, 0, stream>>>(cursor, offs, bsum, N);
    scan2_kernel<<<1, 256, 0, stream>>>(bsum, NSCANB);
    scan3_kernel<<<NSCANB, 256, 0, stream>>>(offs, bsum, cursor, N);
    scatter_kernel<<<(NETOT + 255) / 256, 256, 0, stream>>>(ei, cursor, srcs);

    const int NW = N / 4;  // blocks for one-wave-per-node kernels (256 thr = 4 waves)

    // ---- GAT layer 1: h1 = x@W1^T [N,256]; agg + bias + LN + ReLU -> x1 ----
    gemm_kernel<false, false><<<dim3(N / 64, 4), 256, 0, stream>>>(
        x, W1, hbuf, N, 256, 64, nullptr, nullptr, nullptr);
    gat_scores_kernel<4, 64><<<NW, 256, 0, stream>>>(hbuf, as1, ad1, esb, edb, N);
    gat_agg_kernel<4, 64, true><<<NW, 256, 0, stream>>>(
        hbuf, esb, edb, offs, srcs, bg1, ln1g, ln1b, xbuf, N);

    // ---- GAT layer 2: h2 = x1@W2^T [N,128]; agg -> x2 ----
    gemm_kernel<false, false><<<dim3(N / 64, 2), 256, 0, stream>>>(
        xbuf, W2, hbuf, N, 128, 256, nullptr, nullptr, nullptr);
    gat_scores_kernel<2, 64><<<NW, 256, 0, stream>>>(hbuf, as2, ad2, esb, edb, N);
    gat_agg_kernel<2, 64, true><<<NW, 256, 0, stream>>>(
        hbuf, esb, edb, offs, srcs, bg2, ln2g, ln2b, xbuf, N);

    // ---- GAT layer 3: h3 = x2@W3^T [N,128]; agg + bias -> x3 (no LN/ReLU) ----
    gemm_kernel<false, false><<<dim3(N / 64, 2), 256, 0, stream>>>(
        xbuf, W3, hbuf, N, 128, 128, nullptr, nullptr, nullptr);
    gat_scores_kernel<1, 128><<<NW, 256, 0, stream>>>(hbuf, as3, ad3, esb, edb, N);
    gat_agg_kernel<1, 128, false><<<NW, 256, 0, stream>>>(
        hbuf, esb, edb, offs, srcs, bg3, nullptr, nullptr, x3, N);

    // ---- PointNet (reuse hbuf: p1 = hbuf[N,64], p2 = hbuf+N*64 [N,128]) ----
    float* p1 = hbuf;
    float* p2 = hbuf + (size_t)N * 64;
    pn1_kernel<<<(N * 64 + 255) / 256, 256, 0, stream>>>(pos, pw1, pb1, bn1g, bn1b, p1, N);
    gemm_kernel<true, true><<<dim3(N / 64, 2), 256, 0, stream>>>(
        p1, pw2, p2, N, 128, 64, pb2, bn2g, bn2b);
    gemm_kernel<false, false><<<dim3(N / 64, 2), 256, 0, stream>>>(
        p2, pw3, pf, N, 128, 128, pb3, nullptr, nullptr);

    // ---- fusion: combined = [x3|pf] [N,256]; out = combined@fw^T + fb ----
    concat_kernel<<<(N * 64 + 255) / 256, 256, 0, stream>>>(x3, pf, xbuf, N);
    gemm_kernel<false, false><<<dim3(N / 64, 2), 256, 0, stream>>>(
        xbuf, fw, out, N, 128, 256, fb, nullptr, nullptr);
}

// Round 3
// 630.207 us; speedup vs baseline: 1.3262x; 1.0982x over previous
//
#include <hip/hip_runtime.h>
#include <cstddef>

#define NNODES 40000
#define NEDGES 640000
#define NETOT  (NNODES + NEDGES)
#define NSCANB ((NNODES + 255) / 256)   // 157 scan blocks

typedef unsigned short u16;
typedef unsigned int   u32;

// ---------------- helpers ----------------
__device__ inline float wave_sum(float v) {
#pragma unroll
    for (int o = 32; o > 0; o >>= 1) v += __shfl_xor(v, o);
    return v;
}
__device__ inline float wave_max(float v) {
#pragma unroll
    for (int o = 32; o > 0; o >>= 1) v = fmaxf(v, __shfl_xor(v, o));
    return v;
}
__device__ inline u16 f2bf(float f) {   // round-to-nearest-even f32 -> bf16
    u32 u = __float_as_uint(f);
    return (u16)((u + 0x7fffu + ((u >> 16) & 1u)) >> 16);
}
__device__ inline float bf2f(u16 b) { return __uint_as_float((u32)b << 16); }

// ---------------- CSR build ----------------
__global__ void count_kernel(const int* __restrict__ ei, int* __restrict__ deg) {
    int idx = blockIdx.x * blockDim.x + threadIdx.x;
    if (idx >= NETOT) return;
    int dst = (idx < NEDGES) ? ei[NEDGES + idx] : (idx - NEDGES);
    atomicAdd(&deg[dst], 1);
}

__global__ void scan1_kernel(const int* __restrict__ deg, int* __restrict__ offs,
                             int* __restrict__ bsum, int n) {
    __shared__ int tmp[256];
    int i = blockIdx.x * 256 + threadIdx.x;
    int v = (i < n) ? deg[i] : 0;
    tmp[threadIdx.x] = v;
    __syncthreads();
    int acc = v;
#pragma unroll
    for (int off = 1; off < 256; off <<= 1) {
        int t = (threadIdx.x >= off) ? tmp[threadIdx.x - off] : 0;
        __syncthreads();
        acc += t;
        tmp[threadIdx.x] = acc;
        __syncthreads();
    }
    if (i < n) offs[i] = acc - v;
    if (threadIdx.x == 255) bsum[blockIdx.x] = acc;
}

__global__ void scan2_kernel(int* __restrict__ bsum, int nb) {
    __shared__ int tmp[256];
    int v = (threadIdx.x < nb) ? bsum[threadIdx.x] : 0;
    tmp[threadIdx.x] = v;
    __syncthreads();
    int acc = v;
#pragma unroll
    for (int off = 1; off < 256; off <<= 1) {
        int t = (threadIdx.x >= off) ? tmp[threadIdx.x - off] : 0;
        __syncthreads();
        acc += t;
        tmp[threadIdx.x] = acc;
        __syncthreads();
    }
    if (threadIdx.x < nb) bsum[threadIdx.x] = acc - v;
}

__global__ void scan3_kernel(int* __restrict__ offs, const int* __restrict__ bsum,
                             int* __restrict__ cursor, int n) {
    int i = blockIdx.x * 256 + threadIdx.x;
    if (i < n) {
        int o = offs[i] + bsum[blockIdx.x];
        offs[i] = o;
        cursor[i] = o;
    }
    if (i == 0) offs[n] = NETOT;
}

__global__ void scatter_kernel(const int* __restrict__ ei, int* __restrict__ cursor,
                               int* __restrict__ srcs) {
    int idx = blockIdx.x * blockDim.x + threadIdx.x;
    if (idx >= NETOT) return;
    int src, dst;
    if (idx < NEDGES) { src = ei[idx]; dst = ei[NEDGES + idx]; }
    else              { src = idx - NEDGES; dst = src; }
    int p = atomicAdd(&cursor[dst], 1);
    srcs[p] = src;
}

// ---------------- casts ----------------
__global__ void cast_x_kernel(const float* __restrict__ s, u16* __restrict__ d, int n4) {
    int i = blockIdx.x * blockDim.x + threadIdx.x;
    if (i >= n4) return;
    float4 v = ((const float4*)s)[i];
    ushort4 o; o.x = f2bf(v.x); o.y = f2bf(v.y); o.z = f2bf(v.z); o.w = f2bf(v.w);
    ((ushort4*)d)[i] = o;
}

// all 6 weight matrices in one launch
__global__ void castw_kernel(const float* s0, u16* d0, int n0, const float* s1, u16* d1, int n1,
                             const float* s2, u16* d2, int n2, const float* s3, u16* d3, int n3,
                             const float* s4, u16* d4, int n4, const float* s5, u16* d5, int n5) {
    int i = blockIdx.x * blockDim.x + threadIdx.x;
    if (i < n0) { d0[i] = f2bf(s0[i]); return; } i -= n0;
    if (i < n1) { d1[i] = f2bf(s1[i]); return; } i -= n1;
    if (i < n2) { d2[i] = f2bf(s2[i]); return; } i -= n2;
    if (i < n3) { d3[i] = f2bf(s3[i]); return; } i -= n3;
    if (i < n4) { d4[i] = f2bf(s4[i]); return; } i -= n4;
    if (i < n5) { d5[i] = f2bf(s5[i]); }
}

// ---------------- bf16 MFMA GEMM: C[M,N] = A[M,K] @ B[N,K]^T ----------------
// MODE 0: out bf16, no epilogue (h for GAT)
// MODE 1: out bf16, (v+bias)*bn_g' + bn_b, ReLU (pointnet layer 2)
// MODE 2: out f32, v+bias (pointnet layer 3, fusion)
// grid = (M/64, N/64), block = 256 (4 waves; wave w owns rows [w*16, w*16+16))
template <int MODE>
__global__ void gemm_mfma_kernel(const u16* __restrict__ A, const u16* __restrict__ B,
                                 void* __restrict__ C, int M, int Nn, int K,
                                 const float* __restrict__ bias,
                                 const float* __restrict__ bng, const float* __restrict__ bnb) {
    using bfrag = __attribute__((ext_vector_type(8))) short;
    using ffrag = __attribute__((ext_vector_type(4))) float;
    int wave = threadIdx.x >> 6, lane = threadIdx.x & 63;
    int lm = lane & 15, kg = (lane >> 4) * 8;
    int rowblk = blockIdx.x * 64 + wave * 16;
    int n0 = blockIdx.y * 64;
    const u16* Ap = A + (size_t)(rowblk + lm) * K + kg;
    const u16* Bp = B + (size_t)(n0 + lm) * K + kg;
    ffrag acc[4] = {};
    for (int k0 = 0; k0 < K; k0 += 32) {
        bfrag af  = *(const bfrag*)(Ap + k0);
        bfrag bf0 = *(const bfrag*)(Bp + k0);
        bfrag bf1 = *(const bfrag*)(Bp + (size_t)16 * K + k0);
        bfrag bf2 = *(const bfrag*)(Bp + (size_t)32 * K + k0);
        bfrag bf3 = *(const bfrag*)(Bp + (size_t)48 * K + k0);
        acc[0] = __builtin_amdgcn_mfma_f32_16x16x32_bf16(af, bf0, acc[0], 0, 0, 0);
        acc[1] = __builtin_amdgcn_mfma_f32_16x16x32_bf16(af, bf1, acc[1], 0, 0, 0);
        acc[2] = __builtin_amdgcn_mfma_f32_16x16x32_bf16(af, bf2, acc[2], 0, 0, 0);
        acc[3] = __builtin_amdgcn_mfma_f32_16x16x32_bf16(af, bf3, acc[3], 0, 0, 0);
    }
    int orow = rowblk + (lane >> 4) * 4;   // C/D: col = lane&15, row = (lane>>4)*4 + reg
#pragma unroll
    for (int t = 0; t < 4; t++) {
        int col = n0 + t * 16 + lm;
        float bi = 0.f, g = 1.f, bb = 0.f;
        if (MODE >= 1) bi = bias[col];
        if (MODE == 1) { g = bng[col] * rsqrtf(1.0f + 1e-5f); bb = bnb[col]; }
#pragma unroll
        for (int r = 0; r < 4; r++) {
            float v = acc[t][r];
            if (MODE == 1) { v = (v + bi) * g + bb; v = v > 0.f ? v : 0.f; }
            if (MODE == 2) { v = v + bi; }
            size_t ci = (size_t)(orow + r) * Nn + col;
            if (MODE == 2) ((float*)C)[ci] = v;
            else           ((u16*)C)[ci] = f2bf(v);
        }
    }
}

// ---------------- GAT attention scores (h in bf16) ----------------
template <int H, int C>
__global__ void gat_scores_kernel(const u16* __restrict__ hmat,
                                  const float* __restrict__ as, const float* __restrict__ ad,
                                  float* __restrict__ es, float* __restrict__ ed, int n) {
    constexpr int HC = H * C;
    int wid = (blockIdx.x * blockDim.x + threadIdx.x) >> 6;
    int lane = threadIdx.x & 63;
    if (wid >= n) return;
    const u16* hp = hmat + (size_t)wid * HC;
    float ps[H], pd[H];
#pragma unroll
    for (int hh = 0; hh < H; hh++) { ps[hh] = 0.f; pd[hh] = 0.f; }
#pragma unroll
    for (int f0 = 0; f0 < HC; f0 += 64) {
        const int hh = f0 / C;
        int f = f0 + lane;
        float hv = bf2f(hp[f]);
        ps[hh] += hv * as[f];
        pd[hh] += hv * ad[f];
    }
#pragma unroll
    for (int hh = 0; hh < H; hh++) {
        float s = wave_sum(ps[hh]);
        float d = wave_sum(pd[hh]);
        if (lane == 0) {
            es[(size_t)wid * H + hh] = s;
            ed[(size_t)wid * H + hh] = d;
        }
    }
}

// ---------------- GAT aggregation; h bf16; out bf16 (LNRELU) or f32 ----------------
template <int H, int C, bool LNRELU>
__global__ void gat_agg_kernel(const u16* __restrict__ hmat,
                               const float* __restrict__ es, const float* __restrict__ ed,
                               const int* __restrict__ offs, const int* __restrict__ srcs,
                               const float* __restrict__ bias,
                               const float* __restrict__ lng, const float* __restrict__ lnb,
                               void* __restrict__ out, int n) {
    constexpr int HC = H * C;
    constexpr int VPT = HC / 64;
    int wid = (blockIdx.x * blockDim.x + threadIdx.x) >> 6;
    int lane = threadIdx.x & 63;
    if (wid >= n) return;
    int start = offs[wid], end = offs[wid + 1];

    float edi[H];
#pragma unroll
    for (int hh = 0; hh < H; hh++) edi[hh] = ed[(size_t)wid * H + hh];

    // pass 1: segment max per head
    float m[H];
#pragma unroll
    for (int hh = 0; hh < H; hh++) m[hh] = -1e30f;
    for (int e = start + lane; e < end; e += 64) {
        int s = srcs[e];
#pragma unroll
        for (int hh = 0; hh < H; hh++) {
            float v = es[(size_t)s * H + hh] + edi[hh];
            v = v > 0.f ? v : 0.2f * v;
            m[hh] = fmaxf(m[hh], v);
        }
    }
#pragma unroll
    for (int hh = 0; hh < H; hh++) m[hh] = wave_max(m[hh]);

    // pass 2: exp-sum per head
    float den[H];
#pragma unroll
    for (int hh = 0; hh < H; hh++) den[hh] = 0.f;
    for (int e = start + lane; e < end; e += 64) {
        int s = srcs[e];
#pragma unroll
        for (int hh = 0; hh < H; hh++) {
            float v = es[(size_t)s * H + hh] + edi[hh];
            v = v > 0.f ? v : 0.2f * v;
            den[hh] += __expf(v - m[hh]);
        }
    }
#pragma unroll
    for (int hh = 0; hh < H; hh++) den[hh] = wave_sum(den[hh]) + 1e-16f;

    // pass 3: weighted accumulate; lane owns VPT consecutive features (bf16 gather)
    const int myhead = (lane * VPT) / C;
    float mh = m[myhead];
    float invden = 1.f / den[myhead];
    float edh = edi[myhead];
    float acc[VPT];
#pragma unroll
    for (int j = 0; j < VPT; j++) acc[j] = 0.f;

    for (int e = start; e < end; e++) {
        int s = srcs[e];
        float v = es[(size_t)s * H + myhead] + edh;
        v = v > 0.f ? v : 0.2f * v;
        float w = __expf(v - mh) * invden;
        const u16* hp = hmat + (size_t)s * HC + lane * VPT;
        if constexpr (VPT == 4) {
            uint2 hv = *(const uint2*)hp;
            acc[0] += w * __uint_as_float(hv.x << 16);
            acc[1] += w * __uint_as_float(hv.x & 0xffff0000u);
            acc[2] += w * __uint_as_float(hv.y << 16);
            acc[3] += w * __uint_as_float(hv.y & 0xffff0000u);
        } else {
            u32 hv = *(const u32*)hp;
            acc[0] += w * __uint_as_float(hv << 16);
            acc[1] += w * __uint_as_float(hv & 0xffff0000u);
        }
    }

    int fbase = lane * VPT;
    float y[VPT];
#pragma unroll
    for (int j = 0; j < VPT; j++) y[j] = acc[j] + bias[fbase + j];

    if constexpr (LNRELU) {
        float s1 = 0.f, s2 = 0.f;
#pragma unroll
        for (int j = 0; j < VPT; j++) { s1 += y[j]; s2 += y[j] * y[j]; }
        s1 = wave_sum(s1);
        s2 = wave_sum(s2);
        float mu = s1 / (float)HC;
        float var = s2 / (float)HC - mu * mu;
        float rstd = rsqrtf(var + 1e-5f);
#pragma unroll
        for (int j = 0; j < VPT; j++) {
            float v = (y[j] - mu) * rstd * lng[fbase + j] + lnb[fbase + j];
            y[j] = v > 0.f ? v : 0.f;
        }
        u16* op = (u16*)out + (size_t)wid * HC + fbase;
        if constexpr (VPT == 4) {
            ushort4 o; o.x = f2bf(y[0]); o.y = f2bf(y[1]); o.z = f2bf(y[2]); o.w = f2bf(y[3]);
            *(ushort4*)op = o;
        } else {
            ushort2 o; o.x = f2bf(y[0]); o.y = f2bf(y[1]);
            *(ushort2*)op = o;
        }
    } else {
        float* op = (float*)out + (size_t)wid * HC + fbase;
        if constexpr (VPT == 4) *(float4*)op = make_float4(y[0], y[1], y[2], y[3]);
        else                    *(float2*)op = make_float2(y[0], y[1]);
    }
}

// ---------------- PointNet layer 1 (K=3) + BN + ReLU -> bf16 ----------------
__global__ void pn1_kernel(const float* __restrict__ pos, const float* __restrict__ pw1,
                           const float* __restrict__ pb1, const float* __restrict__ g,
                           const float* __restrict__ b, u16* __restrict__ out, int n) {
    int idx = blockIdx.x * blockDim.x + threadIdx.x;
    if (idx >= n * 64) return;
    int node = idx >> 6, o = idx & 63;
    float p0 = pos[node * 3 + 0], p1 = pos[node * 3 + 1], p2 = pos[node * 3 + 2];
    float v = p0 * pw1[o * 3 + 0] + p1 * pw1[o * 3 + 1] + p2 * pw1[o * 3 + 2] + pb1[o];
    v = v * (g[o] * rsqrtf(1.0f + 1e-5f)) + b[o];
    out[idx] = f2bf(v > 0.f ? v : 0.f);
}

// ---------------- concat [x3 | pos_features] (f32) -> combined bf16 [N,256] ----------------
__global__ void concat_kernel(const float* __restrict__ x3, const float* __restrict__ pf,
                              u16* __restrict__ comb, int n) {
    int idx = blockIdx.x * blockDim.x + threadIdx.x;  // over n*64 float4 groups
    if (idx >= n * 64) return;
    int node = idx >> 6, c4 = idx & 63;
    float4 v = (c4 < 32) ? ((const float4*)x3)[(size_t)node * 32 + c4]
                         : ((const float4*)pf)[(size_t)node * 32 + (c4 - 32)];
    ushort4 o; o.x = f2bf(v.x); o.y = f2bf(v.y); o.z = f2bf(v.z); o.w = f2bf(v.w);
    ((ushort4*)comb)[idx] = o;
}

extern "C" void kernel_launch(void* const* d_in, const int* in_sizes, int n_in,
                              void* d_out, int out_size, void* d_ws, size_t ws_size,
                              hipStream_t stream) {
    const float* x    = (const float*)d_in[0];
    const int*   ei   = (const int*)d_in[1];
    const float* pos  = (const float*)d_in[2];
    const float* W1   = (const float*)d_in[3];
    const float* as1  = (const float*)d_in[4];
    const float* ad1  = (const float*)d_in[5];
    const float* bg1  = (const float*)d_in[6];
    const float* ln1g = (const float*)d_in[7];
    const float* ln1b = (const float*)d_in[8];
    const float* W2   = (const float*)d_in[9];
    const float* as2  = (const float*)d_in[10];
    const float* ad2  = (const float*)d_in[11];
    const float* bg2  = (const float*)d_in[12];
    const float* ln2g = (const float*)d_in[13];
    const float* ln2b = (const float*)d_in[14];
    const float* W3   = (const float*)d_in[15];
    const float* as3  = (const float*)d_in[16];
    const float* ad3  = (const float*)d_in[17];
    const float* bg3  = (const float*)d_in[18];
    const float* pw1  = (const float*)d_in[19];
    const float* pb1  = (const float*)d_in[20];
    const float* bn1g = (const float*)d_in[21];
    const float* bn1b = (const float*)d_in[22];
    const float* pw2  = (const float*)d_in[23];
    const float* pb2  = (const float*)d_in[24];
    const float* bn2g = (const float*)d_in[25];
    const float* bn2b = (const float*)d_in[26];
    const float* pw3  = (const float*)d_in[27];
    const float* pb3  = (const float*)d_in[28];
    const float* fw   = (const float*)d_in[29];
    const float* fb   = (const float*)d_in[30];

    const int N = NNODES;
    float* out = (float*)d_out;                    // [N,128]
    float* x3  = out + (size_t)N * 128;            // [N,128]
    float* pf  = out + (size_t)2 * N * 128;        // [N,128]

    char* ws = (char*)d_ws;
    size_t off = 0;
    auto alloc = [&](size_t bytes) -> void* {
        void* p = ws + off;
        off += (bytes + 255) / 256 * 256;
        return p;
    };
    int*   offs   = (int*)alloc((size_t)(N + 1) * 4);
    int*   cursor = (int*)alloc((size_t)N * 4);
    int*   bsum   = (int*)alloc((size_t)NSCANB * 4);
    int*   srcs   = (int*)alloc((size_t)NETOT * 4);
    float* esb    = (float*)alloc((size_t)N * 4 * 4);
    float* edb    = (float*)alloc((size_t)N * 4 * 4);
    u16*   xc     = (u16*)alloc((size_t)N * 64 * 2);    // x in bf16
    u16*   w1c    = (u16*)alloc(16384 * 2);
    u16*   w2c    = (u16*)alloc(32768 * 2);
    u16*   w3c    = (u16*)alloc(16384 * 2);
    u16*   pw2c   = (u16*)alloc(8192 * 2);
    u16*   pw3c   = (u16*)alloc(16384 * 2);
    u16*   fwc    = (u16*)alloc(32768 * 2);
    u16*   hbufb  = (u16*)alloc((size_t)N * 256 * 2);   // h per layer (bf16)
    u16*   xb     = (u16*)alloc((size_t)N * 256 * 2);   // x1; then x2; then combined (bf16)
    u16*   p1b    = (u16*)alloc((size_t)N * 64 * 2);
    u16*   p2b    = (u16*)alloc((size_t)N * 128 * 2);

    // ---- CSR build ----
    hipMemsetAsync(cursor, 0, (size_t)N * 4, stream);
    count_kernel<<<(NETOT + 255) / 256, 256, 0, stream>>>(ei, cursor);
    scan1_kernel<<<NSCANB, 256, 0, stream>>>(cursor, offs, bsum, N);
    scan2_kernel<<<1, 256, 0, stream>>>(bsum, NSCANB);
    scan3_kernel<<<NSCANB, 256, 0, stream>>>(offs, bsum, cursor, N);
    scatter_kernel<<<(NETOT + 255) / 256, 256, 0, stream>>>(ei, cursor, srcs);

    // ---- casts ----
    cast_x_kernel<<<(N * 16 + 255) / 256, 256, 0, stream>>>(x, xc, N * 16);
    castw_kernel<<<(122880 + 255) / 256, 256, 0, stream>>>(
        W1, w1c, 16384, W2, w2c, 32768, W3, w3c, 16384,
        pw2, pw2c, 8192, pw3, pw3c, 16384, fw, fwc, 32768);

    const int NW = N / 4;   // one-wave-per-node kernels: 256 thr = 4 waves
    const int GB = N / 64;  // 625 GEMM row-blocks

    // ---- GAT layer 1: h1 = x@W1^T [N,256] bf16; agg + bias + LN + ReLU -> x1 bf16 ----
    gemm_mfma_kernel<0><<<dim3(GB, 4), 256, 0, stream>>>(
        xc, w1c, hbufb, N, 256, 64, nullptr, nullptr, nullptr);
    gat_scores_kernel<4, 64><<<NW, 256, 0, stream>>>(hbufb, as1, ad1, esb, edb, N);
    gat_agg_kernel<4, 64, true><<<NW, 256, 0, stream>>>(
        hbufb, esb, edb, offs, srcs, bg1, ln1g, ln1b, xb, N);

    // ---- GAT layer 2 ----
    gemm_mfma_kernel<0><<<dim3(GB, 2), 256, 0, stream>>>(
        xb, w2c, hbufb, N, 128, 256, nullptr, nullptr, nullptr);
    gat_scores_kernel<2, 64><<<NW, 256, 0, stream>>>(hbufb, as2, ad2, esb, edb, N);
    gat_agg_kernel<2, 64, true><<<NW, 256, 0, stream>>>(
        hbufb, esb, edb, offs, srcs, bg2, ln2g, ln2b, xb, N);

    // ---- GAT layer 3: agg + bias -> x3 fp32 (output) ----
    gemm_mfma_kernel<0><<<dim3(GB, 2), 256, 0, stream>>>(
        xb, w3c, hbufb, N, 128, 128, nullptr, nullptr, nullptr);
    gat_scores_kernel<1, 128><<<NW, 256, 0, stream>>>(hbufb, as3, ad3, esb, edb, N);
    gat_agg_kernel<1, 128, false><<<NW, 256, 0, stream>>>(
        hbufb, esb, edb, offs, srcs, bg3, nullptr, nullptr, x3, N);

    // ---- PointNet ----
    pn1_kernel<<<(N * 64 + 255) / 256, 256, 0, stream>>>(pos, pw1, pb1, bn1g, bn1b, p1b, N);
    gemm_mfma_kernel<1><<<dim3(GB, 2), 256, 0, stream>>>(
        p1b, pw2c, p2b, N, 128, 64, pb2, bn2g, bn2b);
    gemm_mfma_kernel<2><<<dim3(GB, 2), 256, 0, stream>>>(
        p2b, pw3c, pf, N, 128, 128, pb3, nullptr, nullptr);

    // ---- fusion: combined = bf16([x3|pf]); out = combined@fw^T + fb ----
    concat_kernel<<<(N * 64 + 255) / 256, 256, 0, stream>>>(x3, pf, xb, N);
    gemm_mfma_kernel<2><<<dim3(GB, 2), 256, 0, stream>>>(
        xb, fwc, out, N, 128, 256, fb, nullptr, nullptr);
}

// Round 4
// 529.414 us; speedup vs baseline: 1.5787x; 1.1904x over previous
//
#include <hip/hip_runtime.h>
#include <cstddef>

#define NNODES 40000
#define NEDGES 640000
#define NETOT  (NNODES + NEDGES)
#define NSCANB ((NNODES + 255) / 256)   // 157 scan blocks

typedef unsigned short u16;
typedef unsigned int   u32;

// ---------------- helpers ----------------
__device__ inline float wave_sum(float v) {
#pragma unroll
    for (int o = 32; o > 0; o >>= 1) v += __shfl_xor(v, o);
    return v;
}
__device__ inline u16 f2bf(float f) {   // round-to-nearest-even f32 -> bf16
    u32 u = __float_as_uint(f);
    return (u16)((u + 0x7fffu + ((u >> 16) & 1u)) >> 16);
}
__device__ inline float bf2f(u16 b) { return __uint_as_float((u32)b << 16); }

// ---------------- CSR build ----------------
__global__ void count_kernel(const int* __restrict__ ei, int* __restrict__ deg) {
    int idx = blockIdx.x * blockDim.x + threadIdx.x;
    if (idx >= NETOT) return;
    int dst = (idx < NEDGES) ? ei[NEDGES + idx] : (idx - NEDGES);
    atomicAdd(&deg[dst], 1);
}

__global__ void scan1_kernel(const int* __restrict__ deg, int* __restrict__ offs,
                             int* __restrict__ bsum, int n) {
    __shared__ int tmp[256];
    int i = blockIdx.x * 256 + threadIdx.x;
    int v = (i < n) ? deg[i] : 0;
    tmp[threadIdx.x] = v;
    __syncthreads();
    int acc = v;
#pragma unroll
    for (int off = 1; off < 256; off <<= 1) {
        int t = (threadIdx.x >= off) ? tmp[threadIdx.x - off] : 0;
        __syncthreads();
        acc += t;
        tmp[threadIdx.x] = acc;
        __syncthreads();
    }
    if (i < n) offs[i] = acc - v;
    if (threadIdx.x == 255) bsum[blockIdx.x] = acc;
}

__global__ void scan2_kernel(int* __restrict__ bsum, int nb) {
    __shared__ int tmp[256];
    int v = (threadIdx.x < nb) ? bsum[threadIdx.x] : 0;
    tmp[threadIdx.x] = v;
    __syncthreads();
    int acc = v;
#pragma unroll
    for (int off = 1; off < 256; off <<= 1) {
        int t = (threadIdx.x >= off) ? tmp[threadIdx.x - off] : 0;
        __syncthreads();
        acc += t;
        tmp[threadIdx.x] = acc;
        __syncthreads();
    }
    if (threadIdx.x < nb) bsum[threadIdx.x] = acc - v;
}

__global__ void scan3_kernel(int* __restrict__ offs, const int* __restrict__ bsum,
                             int* __restrict__ cursor, int n) {
    int i = blockIdx.x * 256 + threadIdx.x;
    if (i < n) {
        int o = offs[i] + bsum[blockIdx.x];
        offs[i] = o;
        cursor[i] = o;
    }
    if (i == 0) offs[n] = NETOT;
}

__global__ void scatter_kernel(const int* __restrict__ ei, int* __restrict__ cursor,
                               int* __restrict__ srcs) {
    int idx = blockIdx.x * blockDim.x + threadIdx.x;
    if (idx >= NETOT) return;
    int src, dst;
    if (idx < NEDGES) { src = ei[idx]; dst = ei[NEDGES + idx]; }
    else              { src = idx - NEDGES; dst = src; }
    int p = atomicAdd(&cursor[dst], 1);
    srcs[p] = src;
}

// ---------------- casts ----------------
__global__ void cast_x_kernel(const float* __restrict__ s, u16* __restrict__ d, int n4) {
    int i = blockIdx.x * blockDim.x + threadIdx.x;
    if (i >= n4) return;
    float4 v = ((const float4*)s)[i];
    ushort4 o; o.x = f2bf(v.x); o.y = f2bf(v.y); o.z = f2bf(v.z); o.w = f2bf(v.w);
    ((ushort4*)d)[i] = o;
}

__global__ void castw_kernel(const float* s0, u16* d0, int n0, const float* s1, u16* d1, int n1,
                             const float* s2, u16* d2, int n2, const float* s3, u16* d3, int n3,
                             const float* s4, u16* d4, int n4, const float* s5, u16* d5, int n5) {
    int i = blockIdx.x * blockDim.x + threadIdx.x;
    if (i < n0) { d0[i] = f2bf(s0[i]); return; } i -= n0;
    if (i < n1) { d1[i] = f2bf(s1[i]); return; } i -= n1;
    if (i < n2) { d2[i] = f2bf(s2[i]); return; } i -= n2;
    if (i < n3) { d3[i] = f2bf(s3[i]); return; } i -= n3;
    if (i < n4) { d4[i] = f2bf(s4[i]); return; } i -= n4;
    if (i < n5) { d5[i] = f2bf(s5[i]); }
}

// ---------------- bf16 MFMA GEMM: C[M,N] = A[M,K] @ B[N,K]^T ----------------
// MODE 0: out bf16 | MODE 1: out bf16, BN+ReLU | MODE 2: out f32, +bias
template <int MODE>
__global__ void gemm_mfma_kernel(const u16* __restrict__ A, const u16* __restrict__ B,
                                 void* __restrict__ C, int M, int Nn, int K,
                                 const float* __restrict__ bias,
                                 const float* __restrict__ bng, const float* __restrict__ bnb) {
    using bfrag = __attribute__((ext_vector_type(8))) short;
    using ffrag = __attribute__((ext_vector_type(4))) float;
    int wave = threadIdx.x >> 6, lane = threadIdx.x & 63;
    int lm = lane & 15, kg = (lane >> 4) * 8;
    int rowblk = blockIdx.x * 64 + wave * 16;
    int n0 = blockIdx.y * 64;
    const u16* Ap = A + (size_t)(rowblk + lm) * K + kg;
    const u16* Bp = B + (size_t)(n0 + lm) * K + kg;
    ffrag acc[4] = {};
    for (int k0 = 0; k0 < K; k0 += 32) {
        bfrag af  = *(const bfrag*)(Ap + k0);
        bfrag bf0 = *(const bfrag*)(Bp + k0);
        bfrag bf1 = *(const bfrag*)(Bp + (size_t)16 * K + k0);
        bfrag bf2 = *(const bfrag*)(Bp + (size_t)32 * K + k0);
        bfrag bf3 = *(const bfrag*)(Bp + (size_t)48 * K + k0);
        acc[0] = __builtin_amdgcn_mfma_f32_16x16x32_bf16(af, bf0, acc[0], 0, 0, 0);
        acc[1] = __builtin_amdgcn_mfma_f32_16x16x32_bf16(af, bf1, acc[1], 0, 0, 0);
        acc[2] = __builtin_amdgcn_mfma_f32_16x16x32_bf16(af, bf2, acc[2], 0, 0, 0);
        acc[3] = __builtin_amdgcn_mfma_f32_16x16x32_bf16(af, bf3, acc[3], 0, 0, 0);
    }
    int orow = rowblk + (lane >> 4) * 4;   // C/D: col = lane&15, row = (lane>>4)*4 + reg
#pragma unroll
    for (int t = 0; t < 4; t++) {
        int col = n0 + t * 16 + lm;
        float bi = 0.f, g = 1.f, bb = 0.f;
        if (MODE >= 1) bi = bias[col];
        if (MODE == 1) { g = bng[col] * rsqrtf(1.0f + 1e-5f); bb = bnb[col]; }
#pragma unroll
        for (int r = 0; r < 4; r++) {
            float v = acc[t][r];
            if (MODE == 1) { v = (v + bi) * g + bb; v = v > 0.f ? v : 0.f; }
            if (MODE == 2) { v = v + bi; }
            size_t ci = (size_t)(orow + r) * Nn + col;
            if (MODE == 2) ((float*)C)[ci] = v;
            else           ((u16*)C)[ci] = f2bf(v);
        }
    }
}

// ---------------- GAT attention scores (h in bf16) ----------------
template <int H, int C>
__global__ void gat_scores_kernel(const u16* __restrict__ hmat,
                                  const float* __restrict__ as, const float* __restrict__ ad,
                                  float* __restrict__ es, float* __restrict__ ed, int n) {
    constexpr int HC = H * C;
    int wid = (blockIdx.x * blockDim.x + threadIdx.x) >> 6;
    int lane = threadIdx.x & 63;
    if (wid >= n) return;
    const u16* hp = hmat + (size_t)wid * HC;
    float ps[H], pd[H];
#pragma unroll
    for (int hh = 0; hh < H; hh++) { ps[hh] = 0.f; pd[hh] = 0.f; }
#pragma unroll
    for (int f0 = 0; f0 < HC; f0 += 64) {
        const int hh = f0 / C;
        int f = f0 + lane;
        float hv = bf2f(hp[f]);
        ps[hh] += hv * as[f];
        pd[hh] += hv * ad[f];
    }
#pragma unroll
    for (int hh = 0; hh < H; hh++) {
        float s = wave_sum(ps[hh]);
        float d = wave_sum(pd[hh]);
        if (lane == 0) {
            es[(size_t)wid * H + hh] = s;
            ed[(size_t)wid * H + hh] = d;
        }
    }
}

// ---------------- GAT alpha: per-edge normalized softmax weight ----------------
// One wave per node. No max-subtraction: e = leakyrelu(es+ed) is bounded (|e|<~5
// with 0.05-scale weights + LN'd activations); exp(e) is fp32-safe and the
// normalized ratio is algebraically identical to the max-subtracted form.
template <int H>
__global__ void gat_alpha_kernel(const float* __restrict__ es, const float* __restrict__ ed,
                                 const int* __restrict__ offs, const int* __restrict__ srcs,
                                 float* __restrict__ abuf, int n) {
    int wid = (blockIdx.x * blockDim.x + threadIdx.x) >> 6;
    int lane = threadIdx.x & 63;
    if (wid >= n) return;
    int start = offs[wid], end = offs[wid + 1];
    float edi[H];
#pragma unroll
    for (int hh = 0; hh < H; hh++) edi[hh] = ed[(size_t)wid * H + hh];
    float den[H];
#pragma unroll
    for (int hh = 0; hh < H; hh++) den[hh] = 0.f;
    for (int e = start + lane; e < end; e += 64) {
        int s = srcs[e];
#pragma unroll
        for (int hh = 0; hh < H; hh++) {
            float v = es[(size_t)s * H + hh] + edi[hh];
            v = v > 0.f ? v : 0.2f * v;
            float w = __expf(v);
            den[hh] += w;
            abuf[(size_t)e * H + hh] = w;
        }
    }
    float inv[H];
#pragma unroll
    for (int hh = 0; hh < H; hh++) inv[hh] = 1.f / (wave_sum(den[hh]) + 1e-16f);
    for (int e = start + lane; e < end; e += 64) {
#pragma unroll
        for (int hh = 0; hh < H; hh++) abuf[(size_t)e * H + hh] *= inv[hh];
    }
}

// ---------------- GAT accumulate: out[dst] = sum alpha*h[src], unroll-4 ----------------
template <int H, int C, bool LNRELU>
__global__ void gat_accum_kernel(const u16* __restrict__ hmat, const float* __restrict__ abuf,
                                 const int* __restrict__ offs, const int* __restrict__ srcs,
                                 const float* __restrict__ bias,
                                 const float* __restrict__ lng, const float* __restrict__ lnb,
                                 void* __restrict__ out, int n) {
    constexpr int HC = H * C;
    constexpr int VPT = HC / 64;
    int wid = (blockIdx.x * blockDim.x + threadIdx.x) >> 6;
    int lane = threadIdx.x & 63;
    if (wid >= n) return;
    int start = offs[wid], end = offs[wid + 1];
    const int myhead = (lane * VPT) / C;

    float acc[VPT];
#pragma unroll
    for (int j = 0; j < VPT; j++) acc[j] = 0.f;

    int e = start;
    for (; e + 4 <= end; e += 4) {
        int s0 = srcs[e], s1 = srcs[e + 1], s2 = srcs[e + 2], s3 = srcs[e + 3];
        float w0 = abuf[(size_t)(e + 0) * H + myhead];
        float w1 = abuf[(size_t)(e + 1) * H + myhead];
        float w2 = abuf[(size_t)(e + 2) * H + myhead];
        float w3 = abuf[(size_t)(e + 3) * H + myhead];
        if constexpr (VPT == 4) {
            uint2 g0 = *(const uint2*)(hmat + (size_t)s0 * HC + lane * 4);
            uint2 g1 = *(const uint2*)(hmat + (size_t)s1 * HC + lane * 4);
            uint2 g2 = *(const uint2*)(hmat + (size_t)s2 * HC + lane * 4);
            uint2 g3 = *(const uint2*)(hmat + (size_t)s3 * HC + lane * 4);
            acc[0] += w0 * __uint_as_float(g0.x << 16);
            acc[1] += w0 * __uint_as_float(g0.x & 0xffff0000u);
            acc[2] += w0 * __uint_as_float(g0.y << 16);
            acc[3] += w0 * __uint_as_float(g0.y & 0xffff0000u);
            acc[0] += w1 * __uint_as_float(g1.x << 16);
            acc[1] += w1 * __uint_as_float(g1.x & 0xffff0000u);
            acc[2] += w1 * __uint_as_float(g1.y << 16);
            acc[3] += w1 * __uint_as_float(g1.y & 0xffff0000u);
            acc[0] += w2 * __uint_as_float(g2.x << 16);
            acc[1] += w2 * __uint_as_float(g2.x & 0xffff0000u);
            acc[2] += w2 * __uint_as_float(g2.y << 16);
            acc[3] += w2 * __uint_as_float(g2.y & 0xffff0000u);
            acc[0] += w3 * __uint_as_float(g3.x << 16);
            acc[1] += w3 * __uint_as_float(g3.x & 0xffff0000u);
            acc[2] += w3 * __uint_as_float(g3.y << 16);
            acc[3] += w3 * __uint_as_float(g3.y & 0xffff0000u);
        } else {
            u32 g0 = *(const u32*)(hmat + (size_t)s0 * HC + lane * 2);
            u32 g1 = *(const u32*)(hmat + (size_t)s1 * HC + lane * 2);
            u32 g2 = *(const u32*)(hmat + (size_t)s2 * HC + lane * 2);
            u32 g3 = *(const u32*)(hmat + (size_t)s3 * HC + lane * 2);
            acc[0] += w0 * __uint_as_float(g0 << 16);
            acc[1] += w0 * __uint_as_float(g0 & 0xffff0000u);
            acc[0] += w1 * __uint_as_float(g1 << 16);
            acc[1] += w1 * __uint_as_float(g1 & 0xffff0000u);
            acc[0] += w2 * __uint_as_float(g2 << 16);
            acc[1] += w2 * __uint_as_float(g2 & 0xffff0000u);
            acc[0] += w3 * __uint_as_float(g3 << 16);
            acc[1] += w3 * __uint_as_float(g3 & 0xffff0000u);
        }
    }
    for (; e < end; e++) {
        int s = srcs[e];
        float w = abuf[(size_t)e * H + myhead];
        if constexpr (VPT == 4) {
            uint2 g = *(const uint2*)(hmat + (size_t)s * HC + lane * 4);
            acc[0] += w * __uint_as_float(g.x << 16);
            acc[1] += w * __uint_as_float(g.x & 0xffff0000u);
            acc[2] += w * __uint_as_float(g.y << 16);
            acc[3] += w * __uint_as_float(g.y & 0xffff0000u);
        } else {
            u32 g = *(const u32*)(hmat + (size_t)s * HC + lane * 2);
            acc[0] += w * __uint_as_float(g << 16);
            acc[1] += w * __uint_as_float(g & 0xffff0000u);
        }
    }

    int fbase = lane * VPT;
    float y[VPT];
#pragma unroll
    for (int j = 0; j < VPT; j++) y[j] = acc[j] + bias[fbase + j];

    if constexpr (LNRELU) {
        float s1 = 0.f, s2 = 0.f;
#pragma unroll
        for (int j = 0; j < VPT; j++) { s1 += y[j]; s2 += y[j] * y[j]; }
        s1 = wave_sum(s1);
        s2 = wave_sum(s2);
        float mu = s1 / (float)HC;
        float var = s2 / (float)HC - mu * mu;
        float rstd = rsqrtf(var + 1e-5f);
#pragma unroll
        for (int j = 0; j < VPT; j++) {
            float v = (y[j] - mu) * rstd * lng[fbase + j] + lnb[fbase + j];
            y[j] = v > 0.f ? v : 0.f;
        }
        u16* op = (u16*)out + (size_t)wid * HC + fbase;
        if constexpr (VPT == 4) {
            ushort4 o; o.x = f2bf(y[0]); o.y = f2bf(y[1]); o.z = f2bf(y[2]); o.w = f2bf(y[3]);
            *(ushort4*)op = o;
        } else {
            ushort2 o; o.x = f2bf(y[0]); o.y = f2bf(y[1]);
            *(ushort2*)op = o;
        }
    } else {
        float* op = (float*)out + (size_t)wid * HC + fbase;
        if constexpr (VPT == 4) *(float4*)op = make_float4(y[0], y[1], y[2], y[3]);
        else                    *(float2*)op = make_float2(y[0], y[1]);
    }
}

// ---------------- PointNet layer 1 (K=3) + BN + ReLU -> bf16 ----------------
__global__ void pn1_kernel(const float* __restrict__ pos, const float* __restrict__ pw1,
                           const float* __restrict__ pb1, const float* __restrict__ g,
                           const float* __restrict__ b, u16* __restrict__ out, int n) {
    int idx = blockIdx.x * blockDim.x + threadIdx.x;
    if (idx >= n * 64) return;
    int node = idx >> 6, o = idx & 63;
    float p0 = pos[node * 3 + 0], p1 = pos[node * 3 + 1], p2 = pos[node * 3 + 2];
    float v = p0 * pw1[o * 3 + 0] + p1 * pw1[o * 3 + 1] + p2 * pw1[o * 3 + 2] + pb1[o];
    v = v * (g[o] * rsqrtf(1.0f + 1e-5f)) + b[o];
    out[idx] = f2bf(v > 0.f ? v : 0.f);
}

// ---------------- concat [x3 | pos_features] (f32) -> combined bf16 [N,256] ----------------
__global__ void concat_kernel(const float* __restrict__ x3, const float* __restrict__ pf,
                              u16* __restrict__ comb, int n) {
    int idx = blockIdx.x * blockDim.x + threadIdx.x;
    if (idx >= n * 64) return;
    int node = idx >> 6, c4 = idx & 63;
    float4 v = (c4 < 32) ? ((const float4*)x3)[(size_t)node * 32 + c4]
                         : ((const float4*)pf)[(size_t)node * 32 + (c4 - 32)];
    ushort4 o; o.x = f2bf(v.x); o.y = f2bf(v.y); o.z = f2bf(v.z); o.w = f2bf(v.w);
    ((ushort4*)comb)[idx] = o;
}

extern "C" void kernel_launch(void* const* d_in, const int* in_sizes, int n_in,
                              void* d_out, int out_size, void* d_ws, size_t ws_size,
                              hipStream_t stream) {
    const float* x    = (const float*)d_in[0];
    const int*   ei   = (const int*)d_in[1];
    const float* pos  = (const float*)d_in[2];
    const float* W1   = (const float*)d_in[3];
    const float* as1  = (const float*)d_in[4];
    const float* ad1  = (const float*)d_in[5];
    const float* bg1  = (const float*)d_in[6];
    const float* ln1g = (const float*)d_in[7];
    const float* ln1b = (const float*)d_in[8];
    const float* W2   = (const float*)d_in[9];
    const float* as2  = (const float*)d_in[10];
    const float* ad2  = (const float*)d_in[11];
    const float* bg2  = (const float*)d_in[12];
    const float* ln2g = (const float*)d_in[13];
    const float* ln2b = (const float*)d_in[14];
    const float* W3   = (const float*)d_in[15];
    const float* as3  = (const float*)d_in[16];
    const float* ad3  = (const float*)d_in[17];
    const float* bg3  = (const float*)d_in[18];
    const float* pw1  = (const float*)d_in[19];
    const float* pb1  = (const float*)d_in[20];
    const float* bn1g = (const float*)d_in[21];
    const float* bn1b = (const float*)d_in[22];
    const float* pw2  = (const float*)d_in[23];
    const float* pb2  = (const float*)d_in[24];
    const float* bn2g = (const float*)d_in[25];
    const float* bn2b = (const float*)d_in[26];
    const float* pw3  = (const float*)d_in[27];
    const float* pb3  = (const float*)d_in[28];
    const float* fw   = (const float*)d_in[29];
    const float* fb   = (const float*)d_in[30];

    const int N = NNODES;
    float* out = (float*)d_out;                    // [N,128]
    float* x3  = out + (size_t)N * 128;            // [N,128]
    float* pf  = out + (size_t)2 * N * 128;        // [N,128]

    char* ws = (char*)d_ws;
    size_t off = 0;
    auto alloc = [&](size_t bytes) -> void* {
        void* p = ws + off;
        off += (bytes + 255) / 256 * 256;
        return p;
    };
    int*   offs   = (int*)alloc((size_t)(N + 1) * 4);
    int*   cursor = (int*)alloc((size_t)N * 4);
    int*   bsum   = (int*)alloc((size_t)NSCANB * 4);
    int*   srcs   = (int*)alloc((size_t)NETOT * 4);
    float* esb    = (float*)alloc((size_t)N * 4 * 4);
    float* edb    = (float*)alloc((size_t)N * 4 * 4);
    float* abuf   = (float*)alloc((size_t)NETOT * 4 * 4);  // per-edge alpha (max H=4)
    u16*   xc     = (u16*)alloc((size_t)N * 64 * 2);
    u16*   w1c    = (u16*)alloc(16384 * 2);
    u16*   w2c    = (u16*)alloc(32768 * 2);
    u16*   w3c    = (u16*)alloc(16384 * 2);
    u16*   pw2c   = (u16*)alloc(8192 * 2);
    u16*   pw3c   = (u16*)alloc(16384 * 2);
    u16*   fwc    = (u16*)alloc(32768 * 2);
    u16*   hbufb  = (u16*)alloc((size_t)N * 256 * 2);
    u16*   xb     = (u16*)alloc((size_t)N * 256 * 2);
    u16*   p1b    = (u16*)alloc((size_t)N * 64 * 2);
    u16*   p2b    = (u16*)alloc((size_t)N * 128 * 2);

    // ---- CSR build ----
    hipMemsetAsync(cursor, 0, (size_t)N * 4, stream);
    count_kernel<<<(NETOT + 255) / 256, 256, 0, stream>>>(ei, cursor);
    scan1_kernel<<<NSCANB, 256, 0, stream>>>(cursor, offs, bsum, N);
    scan2_kernel<<<1, 256, 0, stream>>>(bsum, NSCANB);
    scan3_kernel<<<NSCANB, 256, 0, stream>>>(offs, bsum, cursor, N);
    scatter_kernel<<<(NETOT + 255) / 256, 256, 0, stream>>>(ei, cursor, srcs);

    // ---- casts ----
    cast_x_kernel<<<(N * 16 + 255) / 256, 256, 0, stream>>>(x, xc, N * 16);
    castw_kernel<<<(122880 + 255) / 256, 256, 0, stream>>>(
        W1, w1c, 16384, W2, w2c, 32768, W3, w3c, 16384,
        pw2, pw2c, 8192, pw3, pw3c, 16384, fw, fwc, 32768);

    const int NW = N / 4;   // one-wave-per-node kernels: 256 thr = 4 waves
    const int GB = N / 64;  // 625 GEMM row-blocks

    // ---- GAT layer 1 ----
    gemm_mfma_kernel<0><<<dim3(GB, 4), 256, 0, stream>>>(
        xc, w1c, hbufb, N, 256, 64, nullptr, nullptr, nullptr);
    gat_scores_kernel<4, 64><<<NW, 256, 0, stream>>>(hbufb, as1, ad1, esb, edb, N);
    gat_alpha_kernel<4><<<NW, 256, 0, stream>>>(esb, edb, offs, srcs, abuf, N);
    gat_accum_kernel<4, 64, true><<<NW, 256, 0, stream>>>(
        hbufb, abuf, offs, srcs, bg1, ln1g, ln1b, xb, N);

    // ---- GAT layer 2 ----
    gemm_mfma_kernel<0><<<dim3(GB, 2), 256, 0, stream>>>(
        xb, w2c, hbufb, N, 128, 256, nullptr, nullptr, nullptr);
    gat_scores_kernel<2, 64><<<NW, 256, 0, stream>>>(hbufb, as2, ad2, esb, edb, N);
    gat_alpha_kernel<2><<<NW, 256, 0, stream>>>(esb, edb, offs, srcs, abuf, N);
    gat_accum_kernel<2, 64, true><<<NW, 256, 0, stream>>>(
        hbufb, abuf, offs, srcs, bg2, ln2g, ln2b, xb, N);

    // ---- GAT layer 3 (out f32 -> x3) ----
    gemm_mfma_kernel<0><<<dim3(GB, 2), 256, 0, stream>>>(
        xb, w3c, hbufb, N, 128, 128, nullptr, nullptr, nullptr);
    gat_scores_kernel<1, 128><<<NW, 256, 0, stream>>>(hbufb, as3, ad3, esb, edb, N);
    gat_alpha_kernel<1><<<NW, 256, 0, stream>>>(esb, edb, offs, srcs, abuf, N);
    gat_accum_kernel<1, 128, false><<<NW, 256, 0, stream>>>(
        hbufb, abuf, offs, srcs, bg3, nullptr, nullptr, x3, N);

    // ---- PointNet ----
    pn1_kernel<<<(N * 64 + 255) / 256, 256, 0, stream>>>(pos, pw1, pb1, bn1g, bn1b, p1b, N);
    gemm_mfma_kernel<1><<<dim3(GB, 2), 256, 0, stream>>>(
        p1b, pw2c, p2b, N, 128, 64, pb2, bn2g, bn2b);
    gemm_mfma_kernel<2><<<dim3(GB, 2), 256, 0, stream>>>(
        p2b, pw3c, pf, N, 128, 128, pb3, nullptr, nullptr);

    // ---- fusion ----
    concat_kernel<<<(N * 64 + 255) / 256, 256, 0, stream>>>(x3, pf, xb, N);
    gemm_mfma_kernel<2><<<dim3(GB, 2), 256, 0, stream>>>(
        xb, fwc, out, N, 128, 256, fb, nullptr, nullptr);
}

// Round 5
// 493.543 us; speedup vs baseline: 1.6934x; 1.0727x over previous
//
#include <hip/hip_runtime.h>
#include <cstddef>

#define NNODES 40000
#define NEDGES 640000
#define NETOT  (NNODES + NEDGES)
#define NSCANB ((NNODES + 255) / 256)   // 157 scan blocks
#define DEGCAP 128                       // LDS-staged edges per node (fallback beyond)

typedef unsigned short u16;
typedef unsigned int   u32;

// ---------------- helpers ----------------
__device__ inline float wave_sum(float v) {
#pragma unroll
    for (int o = 32; o > 0; o >>= 1) v += __shfl_xor(v, o);
    return v;
}
__device__ inline u16 f2bf(float f) {   // round-to-nearest-even f32 -> bf16
    u32 u = __float_as_uint(f);
    return (u16)((u + 0x7fffu + ((u >> 16) & 1u)) >> 16);
}
__device__ inline float bf2f(u16 b) { return __uint_as_float((u32)b << 16); }

// ---------------- CSR build ----------------
__global__ void count_kernel(const int* __restrict__ ei, int* __restrict__ deg) {
    int idx = blockIdx.x * blockDim.x + threadIdx.x;
    if (idx >= NETOT) return;
    int dst = (idx < NEDGES) ? ei[NEDGES + idx] : (idx - NEDGES);
    atomicAdd(&deg[dst], 1);
}

__global__ void scan1_kernel(const int* __restrict__ deg, int* __restrict__ offs,
                             int* __restrict__ bsum, int n) {
    __shared__ int tmp[256];
    int i = blockIdx.x * 256 + threadIdx.x;
    int v = (i < n) ? deg[i] : 0;
    tmp[threadIdx.x] = v;
    __syncthreads();
    int acc = v;
#pragma unroll
    for (int off = 1; off < 256; off <<= 1) {
        int t = (threadIdx.x >= off) ? tmp[threadIdx.x - off] : 0;
        __syncthreads();
        acc += t;
        tmp[threadIdx.x] = acc;
        __syncthreads();
    }
    if (i < n) offs[i] = acc - v;
    if (threadIdx.x == 255) bsum[blockIdx.x] = acc;
}

__global__ void scan2_kernel(int* __restrict__ bsum, int nb) {
    __shared__ int tmp[256];
    int v = (threadIdx.x < nb) ? bsum[threadIdx.x] : 0;
    tmp[threadIdx.x] = v;
    __syncthreads();
    int acc = v;
#pragma unroll
    for (int off = 1; off < 256; off <<= 1) {
        int t = (threadIdx.x >= off) ? tmp[threadIdx.x - off] : 0;
        __syncthreads();
        acc += t;
        tmp[threadIdx.x] = acc;
        __syncthreads();
    }
    if (threadIdx.x < nb) bsum[threadIdx.x] = acc - v;
}

__global__ void scan3_kernel(int* __restrict__ offs, const int* __restrict__ bsum,
                             int* __restrict__ cursor, int n) {
    int i = blockIdx.x * 256 + threadIdx.x;
    if (i < n) {
        int o = offs[i] + bsum[blockIdx.x];
        offs[i] = o;
        cursor[i] = o;
    }
    if (i == 0) offs[n] = NETOT;
}

__global__ void scatter_kernel(const int* __restrict__ ei, int* __restrict__ cursor,
                               int* __restrict__ srcs) {
    int idx = blockIdx.x * blockDim.x + threadIdx.x;
    if (idx >= NETOT) return;
    int src, dst;
    if (idx < NEDGES) { src = ei[idx]; dst = ei[NEDGES + idx]; }
    else              { src = idx - NEDGES; dst = src; }
    int p = atomicAdd(&cursor[dst], 1);
    srcs[p] = src;
}

// ---------------- combined cast: x + 6 weight matrices, float4 groups ----------------
__global__ void cast_all_kernel(const float* s0, u16* d0, int n0, const float* s1, u16* d1, int n1,
                                const float* s2, u16* d2, int n2, const float* s3, u16* d3, int n3,
                                const float* s4, u16* d4, int n4, const float* s5, u16* d5, int n5,
                                const float* s6, u16* d6, int n6) {
    int i = blockIdx.x * blockDim.x + threadIdx.x;   // index of a float4 group
    const float* s; u16* d;
    if      (i < n0) { s = s0; d = d0; }
    else if ((i -= n0) < n1) { s = s1; d = d1; }
    else if ((i -= n1) < n2) { s = s2; d = d2; }
    else if ((i -= n2) < n3) { s = s3; d = d3; }
    else if ((i -= n3) < n4) { s = s4; d = d4; }
    else if ((i -= n4) < n5) { s = s5; d = d5; }
    else if ((i -= n5) < n6) { s = s6; d = d6; }
    else return;
    float4 v = ((const float4*)s)[i];
    ushort4 o; o.x = f2bf(v.x); o.y = f2bf(v.y); o.z = f2bf(v.z); o.w = f2bf(v.w);
    ((ushort4*)d)[i] = o;
}

// ---------------- bf16 MFMA GEMM: C[M,N] = A[M,K] @ B[N,K]^T ----------------
// MODE 0: out bf16 | MODE 1: out bf16, BN+ReLU | MODE 2: out f32, +bias
template <int MODE>
__global__ void gemm_mfma_kernel(const u16* __restrict__ A, const u16* __restrict__ B,
                                 void* __restrict__ C, int M, int Nn, int K,
                                 const float* __restrict__ bias,
                                 const float* __restrict__ bng, const float* __restrict__ bnb) {
    using bfrag = __attribute__((ext_vector_type(8))) short;
    using ffrag = __attribute__((ext_vector_type(4))) float;
    int wave = threadIdx.x >> 6, lane = threadIdx.x & 63;
    int lm = lane & 15, kg = (lane >> 4) * 8;
    int rowblk = blockIdx.x * 64 + wave * 16;
    int n0 = blockIdx.y * 64;
    const u16* Ap = A + (size_t)(rowblk + lm) * K + kg;
    const u16* Bp = B + (size_t)(n0 + lm) * K + kg;
    ffrag acc[4] = {};
    for (int k0 = 0; k0 < K; k0 += 32) {
        bfrag af  = *(const bfrag*)(Ap + k0);
        bfrag bf0 = *(const bfrag*)(Bp + k0);
        bfrag bf1 = *(const bfrag*)(Bp + (size_t)16 * K + k0);
        bfrag bf2 = *(const bfrag*)(Bp + (size_t)32 * K + k0);
        bfrag bf3 = *(const bfrag*)(Bp + (size_t)48 * K + k0);
        acc[0] = __builtin_amdgcn_mfma_f32_16x16x32_bf16(af, bf0, acc[0], 0, 0, 0);
        acc[1] = __builtin_amdgcn_mfma_f32_16x16x32_bf16(af, bf1, acc[1], 0, 0, 0);
        acc[2] = __builtin_amdgcn_mfma_f32_16x16x32_bf16(af, bf2, acc[2], 0, 0, 0);
        acc[3] = __builtin_amdgcn_mfma_f32_16x16x32_bf16(af, bf3, acc[3], 0, 0, 0);
    }
    int orow = rowblk + (lane >> 4) * 4;   // C/D: col = lane&15, row = (lane>>4)*4 + reg
#pragma unroll
    for (int t = 0; t < 4; t++) {
        int col = n0 + t * 16 + lm;
        float bi = 0.f, g = 1.f, bb = 0.f;
        if (MODE >= 1) bi = bias[col];
        if (MODE == 1) { g = bng[col] * rsqrtf(1.0f + 1e-5f); bb = bnb[col]; }
#pragma unroll
        for (int r = 0; r < 4; r++) {
            float v = acc[t][r];
            if (MODE == 1) { v = (v + bi) * g + bb; v = v > 0.f ? v : 0.f; }
            if (MODE == 2) { v = v + bi; }
            size_t ci = (size_t)(orow + r) * Nn + col;
            if (MODE == 2) ((float*)C)[ci] = v;
            else           ((u16*)C)[ci] = f2bf(v);
        }
    }
}

// ---------------- GAT attention scores (h in bf16) ----------------
template <int H, int C>
__global__ void gat_scores_kernel(const u16* __restrict__ hmat,
                                  const float* __restrict__ as, const float* __restrict__ ad,
                                  float* __restrict__ es, float* __restrict__ ed, int n) {
    constexpr int HC = H * C;
    int wid = (blockIdx.x * blockDim.x + threadIdx.x) >> 6;
    int lane = threadIdx.x & 63;
    if (wid >= n) return;
    const u16* hp = hmat + (size_t)wid * HC;
    float ps[H], pd[H];
#pragma unroll
    for (int hh = 0; hh < H; hh++) { ps[hh] = 0.f; pd[hh] = 0.f; }
#pragma unroll
    for (int f0 = 0; f0 < HC; f0 += 64) {
        const int hh = f0 / C;
        int f = f0 + lane;
        float hv = bf2f(hp[f]);
        ps[hh] += hv * as[f];
        pd[hh] += hv * ad[f];
    }
#pragma unroll
    for (int hh = 0; hh < H; hh++) {
        float s = wave_sum(ps[hh]);
        float d = wave_sum(pd[hh]);
        if (lane == 0) {
            es[(size_t)wid * H + hh] = s;
            ed[(size_t)wid * H + hh] = d;
        }
    }
}

// ---------------- fused GAT softmax + aggregation, one wave/node ----------------
// Phase 1 (lane-parallel): gather es[src], w=exp(leakyrelu(es+ed)), stage w+src in
// LDS, wave-reduce denominator. No max-subtraction (|e| bounded, fp32 exp safe;
// normalized ratio algebraically identical).
// Phase 2 (serial over edges, unroll-8): acc += (w*inv) * h[src] with LDS weights.
template <int H, int C, bool LNRELU>
__global__ void gat_fused_kernel(const u16* __restrict__ hmat,
                                 const float* __restrict__ es, const float* __restrict__ ed,
                                 const int* __restrict__ offs, const int* __restrict__ srcs,
                                 const float* __restrict__ bias,
                                 const float* __restrict__ lng, const float* __restrict__ lnb,
                                 void* __restrict__ out, int n) {
    constexpr int HC = H * C;
    constexpr int VPT = HC / 64;
    __shared__ float wbuf[4][DEGCAP][H];
    __shared__ int   sbuf[4][DEGCAP];
    int wave = threadIdx.x >> 6;
    int wid = (blockIdx.x * blockDim.x + threadIdx.x) >> 6;
    int lane = threadIdx.x & 63;
    bool alive = wid < n;
    int start = 0, end = 0;
    if (alive) { start = offs[wid]; end = offs[wid + 1]; }

    float edi[H];
#pragma unroll
    for (int hh = 0; hh < H; hh++) edi[hh] = alive ? ed[(size_t)wid * H + hh] : 0.f;

    // ---- phase 1: per-edge weights + denominator ----
    float den[H];
#pragma unroll
    for (int hh = 0; hh < H; hh++) den[hh] = 0.f;
    for (int e = start + lane; e < end; e += 64) {
        int s = srcs[e];
        int le = e - start;
        if (le < DEGCAP) sbuf[wave][le] = s;
        float ev[H];
        if constexpr (H == 4) { float4 t = ((const float4*)es)[s]; ev[0]=t.x; ev[1]=t.y; ev[2]=t.z; ev[3]=t.w; }
        else if constexpr (H == 2) { float2 t = ((const float2*)es)[s]; ev[0]=t.x; ev[1]=t.y; }
        else { ev[0] = es[s]; }
#pragma unroll
        for (int hh = 0; hh < H; hh++) {
            float v = ev[hh] + edi[hh];
            v = v > 0.f ? v : 0.2f * v;
            float w = __expf(v);
            den[hh] += w;
            if (le < DEGCAP) wbuf[wave][le][hh] = w;
        }
    }
    float inv[H];
#pragma unroll
    for (int hh = 0; hh < H; hh++) inv[hh] = 1.f / (wave_sum(den[hh]) + 1e-16f);
    __syncthreads();
    if (!alive) return;

    // ---- phase 2: serial accumulate, unroll-8 ----
    const int myhead = (lane * VPT) / C;
    const float invh = inv[myhead];
    const float edh = edi[myhead];
    float acc[VPT];
#pragma unroll
    for (int j = 0; j < VPT; j++) acc[j] = 0.f;

    constexpr int U = 8;
    int e = start;
    for (; e + U <= end; e += U) {
        int   ss[U];
        float ww[U];
#pragma unroll
        for (int u = 0; u < U; u++) {
            int le = e - start + u;
            if (le < DEGCAP) { ss[u] = sbuf[wave][le]; ww[u] = wbuf[wave][le][myhead]; }
            else {
                ss[u] = srcs[e + u];
                float v = es[(size_t)ss[u] * H + myhead] + edh;
                v = v > 0.f ? v : 0.2f * v;
                ww[u] = __expf(v);
            }
        }
        if constexpr (VPT == 4) {
            uint2 gg[U];
#pragma unroll
            for (int u = 0; u < U; u++) gg[u] = *(const uint2*)(hmat + (size_t)ss[u] * HC + lane * 4);
#pragma unroll
            for (int u = 0; u < U; u++) {
                float w = ww[u] * invh;
                acc[0] += w * __uint_as_float(gg[u].x << 16);
                acc[1] += w * __uint_as_float(gg[u].x & 0xffff0000u);
                acc[2] += w * __uint_as_float(gg[u].y << 16);
                acc[3] += w * __uint_as_float(gg[u].y & 0xffff0000u);
            }
        } else {
            u32 gg[U];
#pragma unroll
            for (int u = 0; u < U; u++) gg[u] = *(const u32*)(hmat + (size_t)ss[u] * HC + lane * 2);
#pragma unroll
            for (int u = 0; u < U; u++) {
                float w = ww[u] * invh;
                acc[0] += w * __uint_as_float(gg[u] << 16);
                acc[1] += w * __uint_as_float(gg[u] & 0xffff0000u);
            }
        }
    }
    for (; e < end; e++) {
        int le = e - start;
        int s; float w;
        if (le < DEGCAP) { s = sbuf[wave][le]; w = wbuf[wave][le][myhead]; }
        else {
            s = srcs[e];
            float v = es[(size_t)s * H + myhead] + edh;
            v = v > 0.f ? v : 0.2f * v;
            w = __expf(v);
        }
        w *= invh;
        if constexpr (VPT == 4) {
            uint2 g = *(const uint2*)(hmat + (size_t)s * HC + lane * 4);
            acc[0] += w * __uint_as_float(g.x << 16);
            acc[1] += w * __uint_as_float(g.x & 0xffff0000u);
            acc[2] += w * __uint_as_float(g.y << 16);
            acc[3] += w * __uint_as_float(g.y & 0xffff0000u);
        } else {
            u32 g = *(const u32*)(hmat + (size_t)s * HC + lane * 2);
            acc[0] += w * __uint_as_float(g << 16);
            acc[1] += w * __uint_as_float(g & 0xffff0000u);
        }
    }

    int fbase = lane * VPT;
    float y[VPT];
#pragma unroll
    for (int j = 0; j < VPT; j++) y[j] = acc[j] + bias[fbase + j];

    if constexpr (LNRELU) {
        float s1 = 0.f, s2 = 0.f;
#pragma unroll
        for (int j = 0; j < VPT; j++) { s1 += y[j]; s2 += y[j] * y[j]; }
        s1 = wave_sum(s1);
        s2 = wave_sum(s2);
        float mu = s1 / (float)HC;
        float var = s2 / (float)HC - mu * mu;
        float rstd = rsqrtf(var + 1e-5f);
#pragma unroll
        for (int j = 0; j < VPT; j++) {
            float v = (y[j] - mu) * rstd * lng[fbase + j] + lnb[fbase + j];
            y[j] = v > 0.f ? v : 0.f;
        }
        u16* op = (u16*)out + (size_t)wid * HC + fbase;
        if constexpr (VPT == 4) {
            ushort4 o; o.x = f2bf(y[0]); o.y = f2bf(y[1]); o.z = f2bf(y[2]); o.w = f2bf(y[3]);
            *(ushort4*)op = o;
        } else {
            ushort2 o; o.x = f2bf(y[0]); o.y = f2bf(y[1]);
            *(ushort2*)op = o;
        }
    } else {
        float* op = (float*)out + (size_t)wid * HC + fbase;
        if constexpr (VPT == 4) *(float4*)op = make_float4(y[0], y[1], y[2], y[3]);
        else                    *(float2*)op = make_float2(y[0], y[1]);
    }
}

// ---------------- PointNet layer 1 (K=3) + BN + ReLU -> bf16 ----------------
__global__ void pn1_kernel(const float* __restrict__ pos, const float* __restrict__ pw1,
                           const float* __restrict__ pb1, const float* __restrict__ g,
                           const float* __restrict__ b, u16* __restrict__ out, int n) {
    int idx = blockIdx.x * blockDim.x + threadIdx.x;
    if (idx >= n * 64) return;
    int node = idx >> 6, o = idx & 63;
    float p0 = pos[node * 3 + 0], p1 = pos[node * 3 + 1], p2 = pos[node * 3 + 2];
    float v = p0 * pw1[o * 3 + 0] + p1 * pw1[o * 3 + 1] + p2 * pw1[o * 3 + 2] + pb1[o];
    v = v * (g[o] * rsqrtf(1.0f + 1e-5f)) + b[o];
    out[idx] = f2bf(v > 0.f ? v : 0.f);
}

// ---------------- concat [x3 | pos_features] (f32) -> combined bf16 [N,256] ----------------
__global__ void concat_kernel(const float* __restrict__ x3, const float* __restrict__ pf,
                              u16* __restrict__ comb, int n) {
    int idx = blockIdx.x * blockDim.x + threadIdx.x;
    if (idx >= n * 64) return;
    int node = idx >> 6, c4 = idx & 63;
    float4 v = (c4 < 32) ? ((const float4*)x3)[(size_t)node * 32 + c4]
                         : ((const float4*)pf)[(size_t)node * 32 + (c4 - 32)];
    ushort4 o; o.x = f2bf(v.x); o.y = f2bf(v.y); o.z = f2bf(v.z); o.w = f2bf(v.w);
    ((ushort4*)comb)[idx] = o;
}

extern "C" void kernel_launch(void* const* d_in, const int* in_sizes, int n_in,
                              void* d_out, int out_size, void* d_ws, size_t ws_size,
                              hipStream_t stream) {
    const float* x    = (const float*)d_in[0];
    const int*   ei   = (const int*)d_in[1];
    const float* pos  = (const float*)d_in[2];
    const float* W1   = (const float*)d_in[3];
    const float* as1  = (const float*)d_in[4];
    const float* ad1  = (const float*)d_in[5];
    const float* bg1  = (const float*)d_in[6];
    const float* ln1g = (const float*)d_in[7];
    const float* ln1b = (const float*)d_in[8];
    const float* W2   = (const float*)d_in[9];
    const float* as2  = (const float*)d_in[10];
    const float* ad2  = (const float*)d_in[11];
    const float* bg2  = (const float*)d_in[12];
    const float* ln2g = (const float*)d_in[13];
    const float* ln2b = (const float*)d_in[14];
    const float* W3   = (const float*)d_in[15];
    const float* as3  = (const float*)d_in[16];
    const float* ad3  = (const float*)d_in[17];
    const float* bg3  = (const float*)d_in[18];
    const float* pw1  = (const float*)d_in[19];
    const float* pb1  = (const float*)d_in[20];
    const float* bn1g = (const float*)d_in[21];
    const float* bn1b = (const float*)d_in[22];
    const float* pw2  = (const float*)d_in[23];
    const float* pb2  = (const float*)d_in[24];
    const float* bn2g = (const float*)d_in[25];
    const float* bn2b = (const float*)d_in[26];
    const float* pw3  = (const float*)d_in[27];
    const float* pb3  = (const float*)d_in[28];
    const float* fw   = (const float*)d_in[29];
    const float* fb   = (const float*)d_in[30];

    const int N = NNODES;
    float* out = (float*)d_out;                    // [N,128]
    float* x3  = out + (size_t)N * 128;            // [N,128]
    float* pf  = out + (size_t)2 * N * 128;        // [N,128]

    char* ws = (char*)d_ws;
    size_t off = 0;
    auto alloc = [&](size_t bytes) -> void* {
        void* p = ws + off;
        off += (bytes + 255) / 256 * 256;
        return p;
    };
    int*   offs   = (int*)alloc((size_t)(N + 1) * 4);
    int*   cursor = (int*)alloc((size_t)N * 4);
    int*   bsum   = (int*)alloc((size_t)NSCANB * 4);
    int*   srcs   = (int*)alloc((size_t)NETOT * 4);
    float* esb    = (float*)alloc((size_t)N * 4 * 4);
    float* edb    = (float*)alloc((size_t)N * 4 * 4);
    u16*   xc     = (u16*)alloc((size_t)N * 64 * 2);
    u16*   w1c    = (u16*)alloc(16384 * 2);
    u16*   w2c    = (u16*)alloc(32768 * 2);
    u16*   w3c    = (u16*)alloc(16384 * 2);
    u16*   pw2c   = (u16*)alloc(8192 * 2);
    u16*   pw3c   = (u16*)alloc(16384 * 2);
    u16*   fwc    = (u16*)alloc(32768 * 2);
    u16*   hbufb  = (u16*)alloc((size_t)N * 256 * 2);
    u16*   xb     = (u16*)alloc((size_t)N * 256 * 2);
    u16*   p1b    = (u16*)alloc((size_t)N * 64 * 2);
    u16*   p2b    = (u16*)alloc((size_t)N * 128 * 2);

    // ---- CSR build ----
    hipMemsetAsync(cursor, 0, (size_t)N * 4, stream);
    count_kernel<<<(NETOT + 255) / 256, 256, 0, stream>>>(ei, cursor);
    scan1_kernel<<<NSCANB, 256, 0, stream>>>(cursor, offs, bsum, N);
    scan2_kernel<<<1, 256, 0, stream>>>(bsum, NSCANB);
    scan3_kernel<<<NSCANB, 256, 0, stream>>>(offs, bsum, cursor, N);
    scatter_kernel<<<(NETOT + 255) / 256, 256, 0, stream>>>(ei, cursor, srcs);

    // ---- casts (x + 6 weights, one kernel; counts are float4 groups) ----
    cast_all_kernel<<<(N * 16 + 30720 + 255) / 256, 256, 0, stream>>>(
        x, xc, N * 16, W1, w1c, 4096, W2, w2c, 8192, W3, w3c, 4096,
        pw2, pw2c, 2048, pw3, pw3c, 4096, fw, fwc, 8192);

    const int NW = N / 4;   // one-wave-per-node kernels: 256 thr = 4 waves
    const int GB = N / 64;  // 625 GEMM row-blocks

    // ---- GAT layer 1 ----
    gemm_mfma_kernel<0><<<dim3(GB, 4), 256, 0, stream>>>(
        xc, w1c, hbufb, N, 256, 64, nullptr, nullptr, nullptr);
    gat_scores_kernel<4, 64><<<NW, 256, 0, stream>>>(hbufb, as1, ad1, esb, edb, N);
    gat_fused_kernel<4, 64, true><<<NW, 256, 0, stream>>>(
        hbufb, esb, edb, offs, srcs, bg1, ln1g, ln1b, xb, N);

    // ---- GAT layer 2 ----
    gemm_mfma_kernel<0><<<dim3(GB, 2), 256, 0, stream>>>(
        xb, w2c, hbufb, N, 128, 256, nullptr, nullptr, nullptr);
    gat_scores_kernel<2, 64><<<NW, 256, 0, stream>>>(hbufb, as2, ad2, esb, edb, N);
    gat_fused_kernel<2, 64, true><<<NW, 256, 0, stream>>>(
        hbufb, esb, edb, offs, srcs, bg2, ln2g, ln2b, xb, N);

    // ---- GAT layer 3 (out f32 -> x3) ----
    gemm_mfma_kernel<0><<<dim3(GB, 2), 256, 0, stream>>>(
        xb, w3c, hbufb, N, 128, 128, nullptr, nullptr, nullptr);
    gat_scores_kernel<1, 128><<<NW, 256, 0, stream>>>(hbufb, as3, ad3, esb, edb, N);
    gat_fused_kernel<1, 128, false><<<NW, 256, 0, stream>>>(
        hbufb, esb, edb, offs, srcs, bg3, nullptr, nullptr, x3, N);

    // ---- PointNet ----
    pn1_kernel<<<(N * 64 + 255) / 256, 256, 0, stream>>>(pos, pw1, pb1, bn1g, bn1b, p1b, N);
    gemm_mfma_kernel<1><<<dim3(GB, 2), 256, 0, stream>>>(
        p1b, pw2c, p2b, N, 128, 64, pb2, bn2g, bn2b);
    gemm_mfma_kernel<2><<<dim3(GB, 2), 256, 0, stream>>>(
        p2b, pw3c, pf, N, 128, 128, pb3, nullptr, nullptr);

    // ---- fusion ----
    concat_kernel<<<(N * 64 + 255) / 256, 256, 0, stream>>>(x3, pf, xb, N);
    gemm_mfma_kernel<2><<<dim3(GB, 2), 256, 0, stream>>>(
        xb, fwc, out, N, 128, 256, fb, nullptr, nullptr);
}

// Round 6
// 457.332 us; speedup vs baseline: 1.8275x; 1.0792x over previous
//
#include <hip/hip_runtime.h>
#include <cstddef>

#define NNODES 40000
#define NEDGES 640000
#define NETOT  (NNODES + NEDGES)
#define NSCANB ((NNODES + 255) / 256)   // 157 scan blocks
#define DEGCAP 128                       // LDS-staged edges per node (fallback beyond)

typedef unsigned short u16;
typedef unsigned int   u32;
using v2f = __attribute__((ext_vector_type(2))) float;

// ---------------- helpers ----------------
__device__ inline float wave_sum(float v) {
#pragma unroll
    for (int o = 32; o > 0; o >>= 1) v += __shfl_xor(v, o);
    return v;
}
__device__ inline u16 f2bf(float f) {   // round-to-nearest-even f32 -> bf16
    u32 u = __float_as_uint(f);
    return (u16)((u + 0x7fffu + ((u >> 16) & 1u)) >> 16);
}
__device__ inline float bf2f(u16 b) { return __uint_as_float((u32)b << 16); }

// ---------------- CSR build ----------------
__global__ void count_kernel(const int* __restrict__ ei, int* __restrict__ deg) {
    int idx = blockIdx.x * blockDim.x + threadIdx.x;
    if (idx >= NETOT) return;
    int dst = (idx < NEDGES) ? ei[NEDGES + idx] : (idx - NEDGES);
    atomicAdd(&deg[dst], 1);
}

__global__ void scan1_kernel(const int* __restrict__ deg, int* __restrict__ offs,
                             int* __restrict__ bsum, int n) {
    __shared__ int tmp[256];
    int i = blockIdx.x * 256 + threadIdx.x;
    int v = (i < n) ? deg[i] : 0;
    tmp[threadIdx.x] = v;
    __syncthreads();
    int acc = v;
#pragma unroll
    for (int off = 1; off < 256; off <<= 1) {
        int t = (threadIdx.x >= off) ? tmp[threadIdx.x - off] : 0;
        __syncthreads();
        acc += t;
        tmp[threadIdx.x] = acc;
        __syncthreads();
    }
    if (i < n) offs[i] = acc - v;
    if (threadIdx.x == 255) bsum[blockIdx.x] = acc;
}

// merged scan2+scan3: every block redundantly scans the (<=256) block sums in LDS,
// then applies its own exclusive prefix; also inits cursor and offs[n].
__global__ void scan23_kernel(int* __restrict__ offs, const int* __restrict__ bsum,
                              int* __restrict__ cursor, int n, int nb) {
    __shared__ int tmp[256];
    int v = (threadIdx.x < nb) ? bsum[threadIdx.x] : 0;
    tmp[threadIdx.x] = v;
    __syncthreads();
    int acc = v;
#pragma unroll
    for (int off = 1; off < 256; off <<= 1) {
        int t = (threadIdx.x >= off) ? tmp[threadIdx.x - off] : 0;
        __syncthreads();
        acc += t;
        tmp[threadIdx.x] = acc;
        __syncthreads();
    }
    int prefix = (blockIdx.x == 0) ? 0 : tmp[blockIdx.x - 1];
    int i = blockIdx.x * 256 + threadIdx.x;
    if (i < n) {
        int o = offs[i] + prefix;
        offs[i] = o;
        cursor[i] = o;
    }
    if (i == 0) offs[n] = NETOT;
}

__global__ void scatter_kernel(const int* __restrict__ ei, int* __restrict__ cursor,
                               int* __restrict__ srcs) {
    int idx = blockIdx.x * blockDim.x + threadIdx.x;
    if (idx >= NETOT) return;
    int src, dst;
    if (idx < NEDGES) { src = ei[idx]; dst = ei[NEDGES + idx]; }
    else              { src = idx - NEDGES; dst = src; }
    int p = atomicAdd(&cursor[dst], 1);
    srcs[p] = src;
}

// ---------------- weights-only cast (float4 groups) ----------------
__global__ void castw_kernel(const float* s0, u16* d0, int n0, const float* s1, u16* d1, int n1,
                             const float* s2, u16* d2, int n2, const float* s3, u16* d3, int n3,
                             const float* s4, u16* d4, int n4, const float* s5, u16* d5, int n5) {
    int i = blockIdx.x * blockDim.x + threadIdx.x;   // float4-group index
    const float* s; u16* d;
    if      (i < n0) { s = s0; d = d0; }
    else if ((i -= n0) < n1) { s = s1; d = d1; }
    else if ((i -= n1) < n2) { s = s2; d = d2; }
    else if ((i -= n2) < n3) { s = s3; d = d3; }
    else if ((i -= n3) < n4) { s = s4; d = d4; }
    else if ((i -= n4) < n5) { s = s5; d = d5; }
    else return;
    float4 v = ((const float4*)s)[i];
    ushort4 o; o.x = f2bf(v.x); o.y = f2bf(v.y); o.z = f2bf(v.z); o.w = f2bf(v.w);
    ((ushort4*)d)[i] = o;
}

// ---------------- GEMM (128-wide N tile) + fused attention scores ----------------
// C[M,Nn] = A[M,K] @ B[Nn,K]^T, h out bf16; es/ed[row,H] from fp32 acc.
// grid = (M/64, Nn/128), block = 256 (wave w owns rows [w*16,w*16+16)).
// HT = 128/C heads per tile; head dot is wave-local (reduce over 16 col-lanes).
template <int H, int C, bool AF32>
__global__ void gemm_scores_kernel(const void* __restrict__ Aptr, const u16* __restrict__ B,
                                   u16* __restrict__ Cout,
                                   const float* __restrict__ as, const float* __restrict__ ad,
                                   float* __restrict__ es, float* __restrict__ ed,
                                   int M, int Nn, int K) {
    constexpr int HT = 128 / C;
    using bfrag = __attribute__((ext_vector_type(8))) short;
    using ffrag = __attribute__((ext_vector_type(4))) float;
    int wave = threadIdx.x >> 6, lane = threadIdx.x & 63;
    int lm = lane & 15, kg = (lane >> 4) * 8;
    int rowblk = blockIdx.x * 64 + wave * 16;
    int n0 = blockIdx.y * 128;
    const u16* Bp = B + (size_t)(n0 + lm) * K + kg;
    ffrag acc[8] = {};
    for (int k0 = 0; k0 < K; k0 += 32) {
        bfrag af;
        if constexpr (AF32) {
            const float* ap = (const float*)Aptr + (size_t)(rowblk + lm) * K + kg + k0;
            float4 a0 = *(const float4*)ap;
            float4 a1 = *(const float4*)(ap + 4);
            af[0] = (short)f2bf(a0.x); af[1] = (short)f2bf(a0.y);
            af[2] = (short)f2bf(a0.z); af[3] = (short)f2bf(a0.w);
            af[4] = (short)f2bf(a1.x); af[5] = (short)f2bf(a1.y);
            af[6] = (short)f2bf(a1.z); af[7] = (short)f2bf(a1.w);
        } else {
            af = *(const bfrag*)((const u16*)Aptr + (size_t)(rowblk + lm) * K + kg + k0);
        }
#pragma unroll
        for (int t = 0; t < 8; t++) {
            bfrag bf = *(const bfrag*)(Bp + (size_t)t * 16 * K + k0);
            acc[t] = __builtin_amdgcn_mfma_f32_16x16x32_bf16(af, bf, acc[t], 0, 0, 0);
        }
    }
    int orow = rowblk + (lane >> 4) * 4;   // C/D: col = lane&15, row = (lane>>4)*4 + reg
    float asv[8], adv[8];
#pragma unroll
    for (int t = 0; t < 8; t++) {
        int fcol = n0 + t * 16 + lm;
        asv[t] = as[fcol]; adv[t] = ad[fcol];
    }
    float ps[4][HT] = {}, pd[4][HT] = {};
#pragma unroll
    for (int t = 0; t < 8; t++) {
        const int hh = t / (C / 16);
#pragma unroll
        for (int r = 0; r < 4; r++) {
            float v = acc[t][r];
            ps[r][hh] += v * asv[t];
            pd[r][hh] += v * adv[t];
            Cout[(size_t)(orow + r) * Nn + n0 + t * 16 + lm] = f2bf(v);
        }
    }
    int hb = blockIdx.y * HT;
#pragma unroll
    for (int r = 0; r < 4; r++)
#pragma unroll
        for (int hh = 0; hh < HT; hh++) {
            float s = ps[r][hh], d = pd[r][hh];
#pragma unroll
            for (int o = 1; o < 16; o <<= 1) { s += __shfl_xor(s, o); d += __shfl_xor(d, o); }
            if (lm == 0) {
                es[(size_t)(orow + r) * H + hb + hh] = s;
                ed[(size_t)(orow + r) * H + hb + hh] = d;
            }
        }
}

// ---------------- plain GEMM (64-wide tile) for pointnet ----------------
// MODE 1: out bf16, BN+ReLU | MODE 2: out f32, +bias
template <int MODE>
__global__ void gemm_mfma_kernel(const u16* __restrict__ A, const u16* __restrict__ B,
                                 void* __restrict__ C, int M, int Nn, int K,
                                 const float* __restrict__ bias,
                                 const float* __restrict__ bng, const float* __restrict__ bnb) {
    using bfrag = __attribute__((ext_vector_type(8))) short;
    using ffrag = __attribute__((ext_vector_type(4))) float;
    int wave = threadIdx.x >> 6, lane = threadIdx.x & 63;
    int lm = lane & 15, kg = (lane >> 4) * 8;
    int rowblk = blockIdx.x * 64 + wave * 16;
    int n0 = blockIdx.y * 64;
    const u16* Ap = A + (size_t)(rowblk + lm) * K + kg;
    const u16* Bp = B + (size_t)(n0 + lm) * K + kg;
    ffrag acc[4] = {};
    for (int k0 = 0; k0 < K; k0 += 32) {
        bfrag af = *(const bfrag*)(Ap + k0);
#pragma unroll
        for (int t = 0; t < 4; t++) {
            bfrag bf = *(const bfrag*)(Bp + (size_t)t * 16 * K + k0);
            acc[t] = __builtin_amdgcn_mfma_f32_16x16x32_bf16(af, bf, acc[t], 0, 0, 0);
        }
    }
    int orow = rowblk + (lane >> 4) * 4;
#pragma unroll
    for (int t = 0; t < 4; t++) {
        int col = n0 + t * 16 + lm;
        float bi = bias[col], g = 1.f, bb = 0.f;
        if (MODE == 1) { g = bng[col] * rsqrtf(1.0f + 1e-5f); bb = bnb[col]; }
#pragma unroll
        for (int r = 0; r < 4; r++) {
            float v = acc[t][r];
            if (MODE == 1) { v = (v + bi) * g + bb; v = v > 0.f ? v : 0.f; }
            else           { v = v + bi; }
            size_t ci = (size_t)(orow + r) * Nn + col;
            if (MODE == 2) ((float*)C)[ci] = v;
            else           ((u16*)C)[ci] = f2bf(v);
        }
    }
}

// ---------------- final GEMM: out = [x3|pf] @ fw^T + fb (concat folded in) ----------------
// A assembled on the fly from f32 x3/pf. Nn=128, K=256. grid=(M/64,1), block=256.
__global__ void gemm_cat_kernel(const float* __restrict__ x3, const float* __restrict__ pf,
                                const u16* __restrict__ B, float* __restrict__ Cout,
                                const float* __restrict__ bias, int M) {
    const int Nn = 128, K = 256;
    using bfrag = __attribute__((ext_vector_type(8))) short;
    using ffrag = __attribute__((ext_vector_type(4))) float;
    int wave = threadIdx.x >> 6, lane = threadIdx.x & 63;
    int lm = lane & 15, kg = (lane >> 4) * 8;
    int rowblk = blockIdx.x * 64 + wave * 16;
    const u16* Bp = B + (size_t)lm * K + kg;
    ffrag acc[8] = {};
    int row = rowblk + lm;
    for (int k0 = 0; k0 < K; k0 += 32) {
        // kg+k0..+7 lies entirely in x3 (k<128) or pf (k>=128) since k0 is 32-aligned
        const float* ap = (k0 < 128) ? (x3 + (size_t)row * 128 + kg + k0)
                                     : (pf + (size_t)row * 128 + kg + k0 - 128);
        float4 a0 = *(const float4*)ap;
        float4 a1 = *(const float4*)(ap + 4);
        bfrag af;
        af[0] = (short)f2bf(a0.x); af[1] = (short)f2bf(a0.y);
        af[2] = (short)f2bf(a0.z); af[3] = (short)f2bf(a0.w);
        af[4] = (short)f2bf(a1.x); af[5] = (short)f2bf(a1.y);
        af[6] = (short)f2bf(a1.z); af[7] = (short)f2bf(a1.w);
#pragma unroll
        for (int t = 0; t < 8; t++) {
            bfrag bf = *(const bfrag*)(Bp + (size_t)t * 16 * K + k0);
            acc[t] = __builtin_amdgcn_mfma_f32_16x16x32_bf16(af, bf, acc[t], 0, 0, 0);
        }
    }
    int orow = rowblk + (lane >> 4) * 4;
#pragma unroll
    for (int t = 0; t < 8; t++) {
        int col = t * 16 + lm;
        float bi = bias[col];
#pragma unroll
        for (int r = 0; r < 4; r++)
            Cout[(size_t)(orow + r) * Nn + col] = acc[t][r] + bi;
    }
}

// ---------------- fused GAT softmax + aggregation, one wave/node ----------------
template <int H, int C, bool LNRELU>
__global__ void gat_fused_kernel(const u16* __restrict__ hmat,
                                 const float* __restrict__ es, const float* __restrict__ ed,
                                 const int* __restrict__ offs, const int* __restrict__ srcs,
                                 const float* __restrict__ bias,
                                 const float* __restrict__ lng, const float* __restrict__ lnb,
                                 void* __restrict__ out, int n) {
    constexpr int HC = H * C;
    constexpr int VPT = HC / 64;
    // wbuf[wave][head][edge]: phase-1 writes stride-1 (conflict-free), phase-2 reads
    // broadcast per 16-lane group; +1 pad decorrelates head banks.
    __shared__ float wbuf[4][H][DEGCAP + 1];
    __shared__ int   sbuf[4][DEGCAP];
    int wave = threadIdx.x >> 6;
    int wid = (blockIdx.x * blockDim.x + threadIdx.x) >> 6;
    int lane = threadIdx.x & 63;
    bool alive = wid < n;
    int start = 0, end = 0;
    if (alive) { start = offs[wid]; end = offs[wid + 1]; }

    float edi[H];
#pragma unroll
    for (int hh = 0; hh < H; hh++) edi[hh] = alive ? ed[(size_t)wid * H + hh] : 0.f;

    // ---- phase 1: per-edge weights + denominator (no max-sub; |e| bounded) ----
    float den[H];
#pragma unroll
    for (int hh = 0; hh < H; hh++) den[hh] = 0.f;
    for (int e = start + lane; e < end; e += 64) {
        int s = srcs[e];
        int le = e - start;
        if (le < DEGCAP) sbuf[wave][le] = s;
        float ev[H];
        if constexpr (H == 4) { float4 t = ((const float4*)es)[s]; ev[0]=t.x; ev[1]=t.y; ev[2]=t.z; ev[3]=t.w; }
        else if constexpr (H == 2) { float2 t = ((const float2*)es)[s]; ev[0]=t.x; ev[1]=t.y; }
        else { ev[0] = es[s]; }
#pragma unroll
        for (int hh = 0; hh < H; hh++) {
            float v = ev[hh] + edi[hh];
            v = v > 0.f ? v : 0.2f * v;
            float w = __expf(v);
            den[hh] += w;
            if (le < DEGCAP) wbuf[wave][hh][le] = w;
        }
    }
    float inv[H];
#pragma unroll
    for (int hh = 0; hh < H; hh++) inv[hh] = 1.f / (wave_sum(den[hh]) + 1e-16f);
    __syncthreads();
    if (!alive) return;

    // ---- phase 2: serial accumulate, unroll-8, packed f32 math ----
    const int myhead = (lane * VPT) / C;
    const float invh = inv[myhead];
    const float edh = edi[myhead];
    v2f a01 = {0.f, 0.f}, a23 = {0.f, 0.f};

    constexpr int U = 8;
    int e = start;
    for (; e + U <= end; e += U) {
        int   ss[U];
        float ww[U];
#pragma unroll
        for (int u = 0; u < U; u++) {
            int le = e - start + u;
            if (le < DEGCAP) { ss[u] = sbuf[wave][le]; ww[u] = wbuf[wave][myhead][le]; }
            else {
                ss[u] = srcs[e + u];
                float v = es[(size_t)ss[u] * H + myhead] + edh;
                v = v > 0.f ? v : 0.2f * v;
                ww[u] = __expf(v);
            }
        }
        if constexpr (VPT == 4) {
            uint2 gg[U];
#pragma unroll
            for (int u = 0; u < U; u++) gg[u] = *(const uint2*)(hmat + (size_t)ss[u] * HC + lane * 4);
#pragma unroll
            for (int u = 0; u < U; u++) {
                float w = ww[u] * invh;
                v2f wv = {w, w};
                v2f h01, h23;
                h01.x = __uint_as_float(gg[u].x << 16);
                h01.y = __uint_as_float(gg[u].x & 0xffff0000u);
                h23.x = __uint_as_float(gg[u].y << 16);
                h23.y = __uint_as_float(gg[u].y & 0xffff0000u);
                a01 += wv * h01;
                a23 += wv * h23;
            }
        } else {
            u32 gg[U];
#pragma unroll
            for (int u = 0; u < U; u++) gg[u] = *(const u32*)(hmat + (size_t)ss[u] * HC + lane * 2);
#pragma unroll
            for (int u = 0; u < U; u++) {
                float w = ww[u] * invh;
                v2f wv = {w, w};
                v2f h01;
                h01.x = __uint_as_float(gg[u] << 16);
                h01.y = __uint_as_float(gg[u] & 0xffff0000u);
                a01 += wv * h01;
            }
        }
    }
    for (; e < end; e++) {
        int le = e - start;
        int s; float w;
        if (le < DEGCAP) { s = sbuf[wave][le]; w = wbuf[wave][myhead][le]; }
        else {
            s = srcs[e];
            float v = es[(size_t)s * H + myhead] + edh;
            v = v > 0.f ? v : 0.2f * v;
            w = __expf(v);
        }
        w *= invh;
        v2f wv = {w, w};
        if constexpr (VPT == 4) {
            uint2 g = *(const uint2*)(hmat + (size_t)s * HC + lane * 4);
            v2f h01, h23;
            h01.x = __uint_as_float(g.x << 16);
            h01.y = __uint_as_float(g.x & 0xffff0000u);
            h23.x = __uint_as_float(g.y << 16);
            h23.y = __uint_as_float(g.y & 0xffff0000u);
            a01 += wv * h01;
            a23 += wv * h23;
        } else {
            u32 g = *(const u32*)(hmat + (size_t)s * HC + lane * 2);
            v2f h01;
            h01.x = __uint_as_float(g << 16);
            h01.y = __uint_as_float(g & 0xffff0000u);
            a01 += wv * h01;
        }
    }

    int fbase = lane * VPT;
    float y[VPT];
    y[0] = a01.x + bias[fbase + 0];
    y[1] = a01.y + bias[fbase + 1];
    if constexpr (VPT == 4) {
        y[2] = a23.x + bias[fbase + 2];
        y[3] = a23.y + bias[fbase + 3];
    }

    if constexpr (LNRELU) {
        float s1 = 0.f, s2 = 0.f;
#pragma unroll
        for (int j = 0; j < VPT; j++) { s1 += y[j]; s2 += y[j] * y[j]; }
        s1 = wave_sum(s1);
        s2 = wave_sum(s2);
        float mu = s1 / (float)HC;
        float var = s2 / (float)HC - mu * mu;
        float rstd = rsqrtf(var + 1e-5f);
#pragma unroll
        for (int j = 0; j < VPT; j++) {
            float v = (y[j] - mu) * rstd * lng[fbase + j] + lnb[fbase + j];
            y[j] = v > 0.f ? v : 0.f;
        }
        u16* op = (u16*)out + (size_t)wid * HC + fbase;
        if constexpr (VPT == 4) {
            ushort4 o; o.x = f2bf(y[0]); o.y = f2bf(y[1]); o.z = f2bf(y[2]); o.w = f2bf(y[3]);
            *(ushort4*)op = o;
        } else {
            ushort2 o; o.x = f2bf(y[0]); o.y = f2bf(y[1]);
            *(ushort2*)op = o;
        }
    } else {
        float* op = (float*)out + (size_t)wid * HC + fbase;
        if constexpr (VPT == 4) *(float4*)op = make_float4(y[0], y[1], y[2], y[3]);
        else                    *(float2*)op = make_float2(y[0], y[1]);
    }
}

// ---------------- PointNet layer 1 (K=3) + BN + ReLU -> bf16 ----------------
__global__ void pn1_kernel(const float* __restrict__ pos, const float* __restrict__ pw1,
                           const float* __restrict__ pb1, const float* __restrict__ g,
                           const float* __restrict__ b, u16* __restrict__ out, int n) {
    int idx = blockIdx.x * blockDim.x + threadIdx.x;
    if (idx >= n * 64) return;
    int node = idx >> 6, o = idx & 63;
    float p0 = pos[node * 3 + 0], p1 = pos[node * 3 + 1], p2 = pos[node * 3 + 2];
    float v = p0 * pw1[o * 3 + 0] + p1 * pw1[o * 3 + 1] + p2 * pw1[o * 3 + 2] + pb1[o];
    v = v * (g[o] * rsqrtf(1.0f + 1e-5f)) + b[o];
    out[idx] = f2bf(v > 0.f ? v : 0.f);
}

extern "C" void kernel_launch(void* const* d_in, const int* in_sizes, int n_in,
                              void* d_out, int out_size, void* d_ws, size_t ws_size,
                              hipStream_t stream) {
    const float* x    = (const float*)d_in[0];
    const int*   ei   = (const int*)d_in[1];
    const float* pos  = (const float*)d_in[2];
    const float* W1   = (const float*)d_in[3];
    const float* as1  = (const float*)d_in[4];
    const float* ad1  = (const float*)d_in[5];
    const float* bg1  = (const float*)d_in[6];
    const float* ln1g = (const float*)d_in[7];
    const float* ln1b = (const float*)d_in[8];
    const float* W2   = (const float*)d_in[9];
    const float* as2  = (const float*)d_in[10];
    const float* ad2  = (const float*)d_in[11];
    const float* bg2  = (const float*)d_in[12];
    const float* ln2g = (const float*)d_in[13];
    const float* ln2b = (const float*)d_in[14];
    const float* W3   = (const float*)d_in[15];
    const float* as3  = (const float*)d_in[16];
    const float* ad3  = (const float*)d_in[17];
    const float* bg3  = (const float*)d_in[18];
    const float* pw1  = (const float*)d_in[19];
    const float* pb1  = (const float*)d_in[20];
    const float* bn1g = (const float*)d_in[21];
    const float* bn1b = (const float*)d_in[22];
    const float* pw2  = (const float*)d_in[23];
    const float* pb2  = (const float*)d_in[24];
    const float* bn2g = (const float*)d_in[25];
    const float* bn2b = (const float*)d_in[26];
    const float* pw3  = (const float*)d_in[27];
    const float* pb3  = (const float*)d_in[28];
    const float* fw   = (const float*)d_in[29];
    const float* fb   = (const float*)d_in[30];

    const int N = NNODES;
    float* out = (float*)d_out;                    // [N,128]
    float* x3  = out + (size_t)N * 128;            // [N,128]
    float* pf  = out + (size_t)2 * N * 128;        // [N,128]

    char* ws = (char*)d_ws;
    size_t off = 0;
    auto alloc = [&](size_t bytes) -> void* {
        void* p = ws + off;
        off += (bytes + 255) / 256 * 256;
        return p;
    };
    int*   offs   = (int*)alloc((size_t)(N + 1) * 4);
    int*   cursor = (int*)alloc((size_t)N * 4);
    int*   bsum   = (int*)alloc((size_t)NSCANB * 4);
    int*   srcs   = (int*)alloc((size_t)NETOT * 4);
    float* esb    = (float*)alloc((size_t)N * 4 * 4);
    float* edb    = (float*)alloc((size_t)N * 4 * 4);
    u16*   w1c    = (u16*)alloc(16384 * 2);
    u16*   w2c    = (u16*)alloc(32768 * 2);
    u16*   w3c    = (u16*)alloc(16384 * 2);
    u16*   pw2c   = (u16*)alloc(8192 * 2);
    u16*   pw3c   = (u16*)alloc(16384 * 2);
    u16*   fwc    = (u16*)alloc(32768 * 2);
    u16*   hbufb  = (u16*)alloc((size_t)N * 256 * 2);
    u16*   xb     = (u16*)alloc((size_t)N * 256 * 2);
    u16*   p1b    = (u16*)alloc((size_t)N * 64 * 2);
    u16*   p2b    = (u16*)alloc((size_t)N * 128 * 2);

    // ---- CSR build ----
    hipMemsetAsync(cursor, 0, (size_t)N * 4, stream);
    count_kernel<<<(NETOT + 255) / 256, 256, 0, stream>>>(ei, cursor);
    scan1_kernel<<<NSCANB, 256, 0, stream>>>(cursor, offs, bsum, N);
    scan23_kernel<<<NSCANB, 256, 0, stream>>>(offs, bsum, cursor, N, NSCANB);
    scatter_kernel<<<(NETOT + 255) / 256, 256, 0, stream>>>(ei, cursor, srcs);

    // ---- weights-only cast (counts = float4 groups) ----
    castw_kernel<<<(30720 + 255) / 256, 256, 0, stream>>>(
        W1, w1c, 4096, W2, w2c, 8192, W3, w3c, 4096,
        pw2, pw2c, 2048, pw3, pw3c, 4096, fw, fwc, 8192);

    const int NW = N / 4;   // one-wave-per-node kernels: 256 thr = 4 waves
    const int GB = N / 64;  // 625 GEMM row-blocks

    // ---- GAT layer 1: gemm(+scores) from f32 x; fused agg -> x1 bf16 ----
    gemm_scores_kernel<4, 64, true><<<dim3(GB, 2), 256, 0, stream>>>(
        x, w1c, hbufb, as1, ad1, esb, edb, N, 256, 64);
    gat_fused_kernel<4, 64, true><<<NW, 256, 0, stream>>>(
        hbufb, esb, edb, offs, srcs, bg1, ln1g, ln1b, xb, N);

    // ---- GAT layer 2 ----
    gemm_scores_kernel<2, 64, false><<<dim3(GB, 1), 256, 0, stream>>>(
        xb, w2c, hbufb, as2, ad2, esb, edb, N, 128, 256);
    gat_fused_kernel<2, 64, true><<<NW, 256, 0, stream>>>(
        hbufb, esb, edb, offs, srcs, bg2, ln2g, ln2b, xb, N);

    // ---- GAT layer 3 (out f32 -> x3) ----
    gemm_scores_kernel<1, 128, false><<<dim3(GB, 1), 256, 0, stream>>>(
        xb, w3c, hbufb, as3, ad3, esb, edb, N, 128, 128);
    gat_fused_kernel<1, 128, false><<<NW, 256, 0, stream>>>(
        hbufb, esb, edb, offs, srcs, bg3, nullptr, nullptr, x3, N);

    // ---- PointNet ----
    pn1_kernel<<<(N * 64 + 255) / 256, 256, 0, stream>>>(pos, pw1, pb1, bn1g, bn1b, p1b, N);
    gemm_mfma_kernel<1><<<dim3(GB, 2), 256, 0, stream>>>(
        p1b, pw2c, p2b, N, 128, 64, pb2, bn2g, bn2b);
    gemm_mfma_kernel<2><<<dim3(GB, 2), 256, 0, stream>>>(
        p2b, pw3c, pf, N, 128, 128, pb3, nullptr, nullptr);

    // ---- fusion (concat folded into GEMM) ----
    gemm_cat_kernel<<<GB, 256, 0, stream>>>(x3, pf, fwc, out, fb, N);
}

// Round 7
// 407.601 us; speedup vs baseline: 2.0505x; 1.1220x over previous
//
#include <hip/hip_runtime.h>
#include <cstddef>

#define NNODES 40000
#define NEDGES 640000
#define NETOT  (NNODES + NEDGES)
#define ELLW   96          // fixed edge slots per node; overflow -> spill list

typedef unsigned short u16;
typedef unsigned int   u32;
using v2f = __attribute__((ext_vector_type(2))) float;

// ---------------- helpers ----------------
__device__ inline float wave_sum(float v) {
#pragma unroll
    for (int o = 32; o > 0; o >>= 1) v += __shfl_xor(v, o);
    return v;
}
__device__ inline u16 f2bf(float f) {   // round-to-nearest-even f32 -> bf16
    u32 u = __float_as_uint(f);
    return (u16)((u + 0x7fffu + ((u >> 16) & 1u)) >> 16);
}

// ---------------- ELL build: one kernel (cnt must be pre-zeroed; ovcnt = cnt[N]) ----------------
__global__ void ell_scatter_kernel(const int* __restrict__ ei, int* __restrict__ cnt,
                                   int* __restrict__ srcs, int2* __restrict__ ovbuf) {
    int idx = blockIdx.x * blockDim.x + threadIdx.x;
    if (idx >= NETOT) return;
    int src, dst;
    if (idx < NEDGES) { src = ei[idx]; dst = ei[NEDGES + idx]; }
    else              { src = idx - NEDGES; dst = src; }
    int p = atomicAdd(&cnt[dst], 1);
    if (p < ELLW) srcs[dst * ELLW + p] = src;
    else {
        int q = atomicAdd(&cnt[NNODES], 1);   // spill (capacity NETOT: never drops)
        ovbuf[q] = make_int2(dst, src);
    }
}

// ---------------- weights-only cast (float4 groups) ----------------
__global__ void castw_kernel(const float* s0, u16* d0, int n0, const float* s1, u16* d1, int n1,
                             const float* s2, u16* d2, int n2, const float* s3, u16* d3, int n3,
                             const float* s4, u16* d4, int n4, const float* s5, u16* d5, int n5) {
    int i = blockIdx.x * blockDim.x + threadIdx.x;   // float4-group index
    const float* s; u16* d;
    if      (i < n0) { s = s0; d = d0; }
    else if ((i -= n0) < n1) { s = s1; d = d1; }
    else if ((i -= n1) < n2) { s = s2; d = d2; }
    else if ((i -= n2) < n3) { s = s3; d = d3; }
    else if ((i -= n3) < n4) { s = s4; d = d4; }
    else if ((i -= n4) < n5) { s = s5; d = d5; }
    else return;
    float4 v = ((const float4*)s)[i];
    ushort4 o; o.x = f2bf(v.x); o.y = f2bf(v.y); o.z = f2bf(v.z); o.w = f2bf(v.w);
    ((ushort4*)d)[i] = o;
}

// ---------------- GEMM (128-wide N tile) + fused attention scores ----------------
template <int H, int C, bool AF32>
__global__ void gemm_scores_kernel(const void* __restrict__ Aptr, const u16* __restrict__ B,
                                   u16* __restrict__ Cout,
                                   const float* __restrict__ as, const float* __restrict__ ad,
                                   float* __restrict__ es, float* __restrict__ ed,
                                   int M, int Nn, int K) {
    constexpr int HT = 128 / C;
    using bfrag = __attribute__((ext_vector_type(8))) short;
    using ffrag = __attribute__((ext_vector_type(4))) float;
    int wave = threadIdx.x >> 6, lane = threadIdx.x & 63;
    int lm = lane & 15, kg = (lane >> 4) * 8;
    int rowblk = blockIdx.x * 64 + wave * 16;
    int n0 = blockIdx.y * 128;
    const u16* Bp = B + (size_t)(n0 + lm) * K + kg;
    ffrag acc[8] = {};
    for (int k0 = 0; k0 < K; k0 += 32) {
        bfrag af;
        if constexpr (AF32) {
            const float* ap = (const float*)Aptr + (size_t)(rowblk + lm) * K + kg + k0;
            float4 a0 = *(const float4*)ap;
            float4 a1 = *(const float4*)(ap + 4);
            af[0] = (short)f2bf(a0.x); af[1] = (short)f2bf(a0.y);
            af[2] = (short)f2bf(a0.z); af[3] = (short)f2bf(a0.w);
            af[4] = (short)f2bf(a1.x); af[5] = (short)f2bf(a1.y);
            af[6] = (short)f2bf(a1.z); af[7] = (short)f2bf(a1.w);
        } else {
            af = *(const bfrag*)((const u16*)Aptr + (size_t)(rowblk + lm) * K + kg + k0);
        }
#pragma unroll
        for (int t = 0; t < 8; t++) {
            bfrag bf = *(const bfrag*)(Bp + (size_t)t * 16 * K + k0);
            acc[t] = __builtin_amdgcn_mfma_f32_16x16x32_bf16(af, bf, acc[t], 0, 0, 0);
        }
    }
    int orow = rowblk + (lane >> 4) * 4;   // C/D: col = lane&15, row = (lane>>4)*4 + reg
    float asv[8], adv[8];
#pragma unroll
    for (int t = 0; t < 8; t++) {
        int fcol = n0 + t * 16 + lm;
        asv[t] = as[fcol]; adv[t] = ad[fcol];
    }
    float ps[4][HT] = {}, pd[4][HT] = {};
#pragma unroll
    for (int t = 0; t < 8; t++) {
        const int hh = t / (C / 16);
#pragma unroll
        for (int r = 0; r < 4; r++) {
            float v = acc[t][r];
            ps[r][hh] += v * asv[t];
            pd[r][hh] += v * adv[t];
            Cout[(size_t)(orow + r) * Nn + n0 + t * 16 + lm] = f2bf(v);
        }
    }
    int hb = blockIdx.y * HT;
#pragma unroll
    for (int r = 0; r < 4; r++)
#pragma unroll
        for (int hh = 0; hh < HT; hh++) {
            float s = ps[r][hh], d = pd[r][hh];
#pragma unroll
            for (int o = 1; o < 16; o <<= 1) { s += __shfl_xor(s, o); d += __shfl_xor(d, o); }
            if (lm == 0) {
                es[(size_t)(orow + r) * H + hb + hh] = s;
                ed[(size_t)(orow + r) * H + hb + hh] = d;
            }
        }
}

// ---------------- fused GAT softmax + aggregation, one wave/node, ELL layout ----------------
template <int H, int C, bool LNRELU>
__global__ void gat_fused_kernel(const u16* __restrict__ hmat,
                                 const float* __restrict__ es, const float* __restrict__ ed,
                                 const int* __restrict__ cnt, const int* __restrict__ srcs,
                                 const int2* __restrict__ ovbuf,
                                 const float* __restrict__ bias,
                                 const float* __restrict__ lng, const float* __restrict__ lnb,
                                 void* __restrict__ out, int n) {
    constexpr int HC = H * C;
    constexpr int VPT = HC / 64;
    constexpr int SH = (HC == 256) ? 9 : 8;      // byte-offset shift for h rows
    __shared__ float wbuf[4][H][100];            // row 400B (16B-aligned), banks decorrelated
    __shared__ int   sbuf[4][ELLW];              // byte offsets into hmat
    int wave = threadIdx.x >> 6;
    int wid = (blockIdx.x * blockDim.x + threadIdx.x) >> 6;
    int lane = threadIdx.x & 63;
    if (wid >= n) return;

    int degt = cnt[wid];
    int mainc = degt < ELLW ? degt : ELLW;
    int base = wid * ELLW;

    float edi[H];
#pragma unroll
    for (int hh = 0; hh < H; hh++) edi[hh] = ed[(size_t)wid * H + hh];

    // ---- phase 1: per-edge weights + denominator (no max-sub; |e| bounded) ----
    float den[H];
#pragma unroll
    for (int hh = 0; hh < H; hh++) den[hh] = 0.f;
    for (int i = lane; i < mainc; i += 64) {
        int s = srcs[base + i];
        sbuf[wave][i] = s << SH;
        float ev[H];
        if constexpr (H == 4) { float4 t = ((const float4*)es)[s]; ev[0]=t.x; ev[1]=t.y; ev[2]=t.z; ev[3]=t.w; }
        else if constexpr (H == 2) { float2 t = ((const float2*)es)[s]; ev[0]=t.x; ev[1]=t.y; }
        else { ev[0] = es[s]; }
#pragma unroll
        for (int hh = 0; hh < H; hh++) {
            float v = ev[hh] + edi[hh];
            v = v > 0.f ? v : 0.2f * v;
            float w = __expf(v);
            den[hh] += w;
            wbuf[wave][hh][i] = w;
        }
    }
    int ovn = 0;
    if (degt > ELLW) {                            // rare spill path: add to denominator
        ovn = cnt[n];
        for (int j = lane; j < ovn; j += 64) {
            int2 t = ovbuf[j];
            if (t.x == wid) {
#pragma unroll
                for (int hh = 0; hh < H; hh++) {
                    float v = es[(size_t)t.y * H + hh] + edi[hh];
                    v = v > 0.f ? v : 0.2f * v;
                    den[hh] += __expf(v);
                }
            }
        }
    }
    float inv[H];
#pragma unroll
    for (int hh = 0; hh < H; hh++) inv[hh] = 1.f / (wave_sum(den[hh]) + 1e-16f);
    // pre-scale LDS weights (wave-synchronous; no barrier needed)
    for (int i = lane; i < mainc; i += 64)
#pragma unroll
        for (int hh = 0; hh < H; hh++) wbuf[wave][hh][i] *= inv[hh];

    // ---- phase 2: serial accumulate, unroll-8, b128 LDS batches ----
    const int myhead = (lane * VPT) / C;
    const int loff = lane * (VPT * 2);
    v2f a01 = {0.f, 0.f}, a23 = {0.f, 0.f};

    int e = 0;
    for (; e + 8 <= mainc; e += 8) {
        int4   o0 = *(const int4*)&sbuf[wave][e];
        int4   o1 = *(const int4*)&sbuf[wave][e + 4];
        float4 w0 = *(const float4*)&wbuf[wave][myhead][e];
        float4 w1 = *(const float4*)&wbuf[wave][myhead][e + 4];
        int   oo[8] = {o0.x, o0.y, o0.z, o0.w, o1.x, o1.y, o1.z, o1.w};
        float ww[8] = {w0.x, w0.y, w0.z, w0.w, w1.x, w1.y, w1.z, w1.w};
        if constexpr (VPT == 4) {
            uint2 gg[8];
#pragma unroll
            for (int u = 0; u < 8; u++)
                gg[u] = *(const uint2*)((const char*)hmat + (size_t)(u32)oo[u] + loff);
#pragma unroll
            for (int u = 0; u < 8; u++) {
                v2f wv = {ww[u], ww[u]};
                v2f h01, h23;
                h01.x = __uint_as_float(gg[u].x << 16);
                h01.y = __uint_as_float(gg[u].x & 0xffff0000u);
                h23.x = __uint_as_float(gg[u].y << 16);
                h23.y = __uint_as_float(gg[u].y & 0xffff0000u);
                a01 += wv * h01;
                a23 += wv * h23;
            }
        } else {
            u32 gg[8];
#pragma unroll
            for (int u = 0; u < 8; u++)
                gg[u] = *(const u32*)((const char*)hmat + (size_t)(u32)oo[u] + loff);
#pragma unroll
            for (int u = 0; u < 8; u++) {
                v2f wv = {ww[u], ww[u]};
                v2f h01;
                h01.x = __uint_as_float(gg[u] << 16);
                h01.y = __uint_as_float(gg[u] & 0xffff0000u);
                a01 += wv * h01;
            }
        }
    }
    for (; e < mainc; e++) {
        int off = sbuf[wave][e];
        float w = wbuf[wave][myhead][e];
        v2f wv = {w, w};
        if constexpr (VPT == 4) {
            uint2 g = *(const uint2*)((const char*)hmat + (size_t)(u32)off + loff);
            v2f h01, h23;
            h01.x = __uint_as_float(g.x << 16);
            h01.y = __uint_as_float(g.x & 0xffff0000u);
            h23.x = __uint_as_float(g.y << 16);
            h23.y = __uint_as_float(g.y & 0xffff0000u);
            a01 += wv * h01;
            a23 += wv * h23;
        } else {
            u32 g = *(const u32*)((const char*)hmat + (size_t)(u32)off + loff);
            v2f h01;
            h01.x = __uint_as_float(g << 16);
            h01.y = __uint_as_float(g & 0xffff0000u);
            a01 += wv * h01;
        }
    }
    if (degt > ELLW) {                            // rare spill accumulate
        const float invh = inv[myhead];
        const float edh = edi[myhead];
        for (int j = 0; j < ovn; j++) {
            int2 t = ovbuf[j];
            if (t.x != wid) continue;
            float v = es[(size_t)t.y * H + myhead] + edh;
            v = v > 0.f ? v : 0.2f * v;
            float w = __expf(v) * invh;
            v2f wv = {w, w};
            if constexpr (VPT == 4) {
                uint2 g = *(const uint2*)((const char*)hmat + ((size_t)t.y << SH) + loff);
                v2f h01, h23;
                h01.x = __uint_as_float(g.x << 16);
                h01.y = __uint_as_float(g.x & 0xffff0000u);
                h23.x = __uint_as_float(g.y << 16);
                h23.y = __uint_as_float(g.y & 0xffff0000u);
                a01 += wv * h01;
                a23 += wv * h23;
            } else {
                u32 g = *(const u32*)((const char*)hmat + ((size_t)t.y << SH) + loff);
                v2f h01;
                h01.x = __uint_as_float(g << 16);
                h01.y = __uint_as_float(g & 0xffff0000u);
                a01 += wv * h01;
            }
        }
    }

    int fbase = lane * VPT;
    float y[VPT];
    y[0] = a01.x + bias[fbase + 0];
    y[1] = a01.y + bias[fbase + 1];
    if constexpr (VPT == 4) {
        y[2] = a23.x + bias[fbase + 2];
        y[3] = a23.y + bias[fbase + 3];
    }

    if constexpr (LNRELU) {
        float s1 = 0.f, s2 = 0.f;
#pragma unroll
        for (int j = 0; j < VPT; j++) { s1 += y[j]; s2 += y[j] * y[j]; }
        s1 = wave_sum(s1);
        s2 = wave_sum(s2);
        float mu = s1 / (float)HC;
        float var = s2 / (float)HC - mu * mu;
        float rstd = rsqrtf(var + 1e-5f);
#pragma unroll
        for (int j = 0; j < VPT; j++) {
            float v = (y[j] - mu) * rstd * lng[fbase + j] + lnb[fbase + j];
            y[j] = v > 0.f ? v : 0.f;
        }
        u16* op = (u16*)out + (size_t)wid * HC + fbase;
        if constexpr (VPT == 4) {
            ushort4 o; o.x = f2bf(y[0]); o.y = f2bf(y[1]); o.z = f2bf(y[2]); o.w = f2bf(y[3]);
            *(ushort4*)op = o;
        } else {
            ushort2 o; o.x = f2bf(y[0]); o.y = f2bf(y[1]);
            *(ushort2*)op = o;
        }
    } else {
        float* op = (float*)out + (size_t)wid * HC + fbase;
        if constexpr (VPT == 4) *(float4*)op = make_float4(y[0], y[1], y[2], y[3]);
        else                    *(float2*)op = make_float2(y[0], y[1]);
    }
}

// ---------------- PointNet layers 1+2 fused: p2 = relu(bn2(relu(bn1(pos@pw1^T))@pw2^T)) ----------------
// A-fragments (p1) computed on the fly from pos. Nn=128, K=64. grid=(M/64), block=256.
__global__ void gemm_pn12_kernel(const float* __restrict__ pos,
                                 const float* __restrict__ pw1, const float* __restrict__ pb1,
                                 const float* __restrict__ bn1g, const float* __restrict__ bn1b,
                                 const u16* __restrict__ B, u16* __restrict__ Cout,
                                 const float* __restrict__ pb2,
                                 const float* __restrict__ bn2g, const float* __restrict__ bn2b,
                                 int M) {
    const int Nn = 128, K = 64;
    using bfrag = __attribute__((ext_vector_type(8))) short;
    using ffrag = __attribute__((ext_vector_type(4))) float;
    int wave = threadIdx.x >> 6, lane = threadIdx.x & 63;
    int lm = lane & 15, kg = (lane >> 4) * 8;
    int rowblk = blockIdx.x * 64 + wave * 16;
    int row = rowblk + lm;
    float p0 = pos[row * 3 + 0], p1 = pos[row * 3 + 1], p2 = pos[row * 3 + 2];
    const u16* Bp = B + (size_t)lm * K + kg;
    const float bnscale = rsqrtf(1.0f + 1e-5f);
    ffrag acc[8] = {};
#pragma unroll
    for (int k0 = 0; k0 < K; k0 += 32) {
        bfrag af;
#pragma unroll
        for (int j = 0; j < 8; j++) {
            int k = kg + k0 + j;
            float v = p0 * pw1[k * 3 + 0] + p1 * pw1[k * 3 + 1] + p2 * pw1[k * 3 + 2] + pb1[k];
            v = v * (bn1g[k] * bnscale) + bn1b[k];
            v = v > 0.f ? v : 0.f;
            af[j] = (short)f2bf(v);
        }
#pragma unroll
        for (int t = 0; t < 8; t++) {
            bfrag bf = *(const bfrag*)(Bp + (size_t)t * 16 * K + k0);
            acc[t] = __builtin_amdgcn_mfma_f32_16x16x32_bf16(af, bf, acc[t], 0, 0, 0);
        }
    }
    int orow = rowblk + (lane >> 4) * 4;
#pragma unroll
    for (int t = 0; t < 8; t++) {
        int col = t * 16 + lm;
        float bi = pb2[col], g = bn2g[col] * bnscale, bb = bn2b[col];
#pragma unroll
        for (int r = 0; r < 4; r++) {
            float v = (acc[t][r] + bi) * g + bb;
            v = v > 0.f ? v : 0.f;
            Cout[(size_t)(orow + r) * Nn + col] = f2bf(v);
        }
    }
}

// ---------------- fused: pf = p2@pw3^T + pb3; out = [x3|pf]@fw^T + fb ----------------
// Stage 1 writes pf (output) and stages the tile in LDS; stage 2 consumes it.
__global__ void gemm_pw3cat_kernel(const u16* __restrict__ p2, const u16* __restrict__ Bpw3,
                                   const float* __restrict__ pb3, float* __restrict__ pf,
                                   const float* __restrict__ x3, const u16* __restrict__ Bfw,
                                   const float* __restrict__ fb, float* __restrict__ outp,
                                   int M) {
    using bfrag = __attribute__((ext_vector_type(8))) short;
    using ffrag = __attribute__((ext_vector_type(4))) float;
    __shared__ float pft[64][132];   // stride 132: bank offset 4/row, 16B-aligned rows
    int wave = threadIdx.x >> 6, lane = threadIdx.x & 63;
    int lm = lane & 15, kg = (lane >> 4) * 8;
    int rowblk = blockIdx.x * 64 + wave * 16;

    // ---- stage 1: pf tile (K=128, Nn=128) ----
    {
        const u16* Ap = p2 + (size_t)(rowblk + lm) * 128 + kg;
        const u16* Bp = Bpw3 + (size_t)lm * 128 + kg;
        ffrag acc[8] = {};
#pragma unroll
        for (int k0 = 0; k0 < 128; k0 += 32) {
            bfrag af = *(const bfrag*)(Ap + k0);
#pragma unroll
            for (int t = 0; t < 8; t++) {
                bfrag bf = *(const bfrag*)(Bp + (size_t)t * 16 * 128 + k0);
                acc[t] = __builtin_amdgcn_mfma_f32_16x16x32_bf16(af, bf, acc[t], 0, 0, 0);
            }
        }
        int orow = rowblk + (lane >> 4) * 4;
        int lrow = wave * 16 + (lane >> 4) * 4;
#pragma unroll
        for (int t = 0; t < 8; t++) {
            int col = t * 16 + lm;
            float bi = pb3[col];
#pragma unroll
            for (int r = 0; r < 4; r++) {
                float v = acc[t][r] + bi;
                pf[(size_t)(orow + r) * 128 + col] = v;
                pft[lrow + r][col] = v;
            }
        }
    }
    __syncthreads();

    // ---- stage 2: out = [x3|pf]@fw^T + fb (K=256, Nn=128) ----
    {
        const u16* Bp = Bfw + (size_t)lm * 256 + kg;
        ffrag acc[8] = {};
        int row = rowblk + lm, lrow = wave * 16 + lm;
#pragma unroll
        for (int k0 = 0; k0 < 256; k0 += 32) {
            bfrag af;
            if (k0 < 128) {
                const float* ap = x3 + (size_t)row * 128 + kg + k0;
                float4 a0 = *(const float4*)ap;
                float4 a1 = *(const float4*)(ap + 4);
                af[0] = (short)f2bf(a0.x); af[1] = (short)f2bf(a0.y);
                af[2] = (short)f2bf(a0.z); af[3] = (short)f2bf(a0.w);
                af[4] = (short)f2bf(a1.x); af[5] = (short)f2bf(a1.y);
                af[6] = (short)f2bf(a1.z); af[7] = (short)f2bf(a1.w);
            } else {
                const float* ap = &pft[lrow][kg + k0 - 128];
                float4 a0 = *(const float4*)ap;
                float4 a1 = *(const float4*)(ap + 4);
                af[0] = (short)f2bf(a0.x); af[1] = (short)f2bf(a0.y);
                af[2] = (short)f2bf(a0.z); af[3] = (short)f2bf(a0.w);
                af[4] = (short)f2bf(a1.x); af[5] = (short)f2bf(a1.y);
                af[6] = (short)f2bf(a1.z); af[7] = (short)f2bf(a1.w);
            }
#pragma unroll
            for (int t = 0; t < 8; t++) {
                bfrag bf = *(const bfrag*)(Bp + (size_t)t * 16 * 256 + k0);
                acc[t] = __builtin_amdgcn_mfma_f32_16x16x32_bf16(af, bf, acc[t], 0, 0, 0);
            }
        }
        int orow = rowblk + (lane >> 4) * 4;
#pragma unroll
        for (int t = 0; t < 8; t++) {
            int col = t * 16 + lm;
            float bi = fb[col];
#pragma unroll
            for (int r = 0; r < 4; r++)
                outp[(size_t)(orow + r) * 128 + col] = acc[t][r] + bi;
        }
    }
}

extern "C" void kernel_launch(void* const* d_in, const int* in_sizes, int n_in,
                              void* d_out, int out_size, void* d_ws, size_t ws_size,
                              hipStream_t stream) {
    const float* x    = (const float*)d_in[0];
    const int*   ei   = (const int*)d_in[1];
    const float* pos  = (const float*)d_in[2];
    const float* W1   = (const float*)d_in[3];
    const float* as1  = (const float*)d_in[4];
    const float* ad1  = (const float*)d_in[5];
    const float* bg1  = (const float*)d_in[6];
    const float* ln1g = (const float*)d_in[7];
    const float* ln1b = (const float*)d_in[8];
    const float* W2   = (const float*)d_in[9];
    const float* as2  = (const float*)d_in[10];
    const float* ad2  = (const float*)d_in[11];
    const float* bg2  = (const float*)d_in[12];
    const float* ln2g = (const float*)d_in[13];
    const float* ln2b = (const float*)d_in[14];
    const float* W3   = (const float*)d_in[15];
    const float* as3  = (const float*)d_in[16];
    const float* ad3  = (const float*)d_in[17];
    const float* bg3  = (const float*)d_in[18];
    const float* pw1  = (const float*)d_in[19];
    const float* pb1  = (const float*)d_in[20];
    const float* bn1g = (const float*)d_in[21];
    const float* bn1b = (const float*)d_in[22];
    const float* pw2  = (const float*)d_in[23];
    const float* pb2  = (const float*)d_in[24];
    const float* bn2g = (const float*)d_in[25];
    const float* bn2b = (const float*)d_in[26];
    const float* pw3  = (const float*)d_in[27];
    const float* pb3  = (const float*)d_in[28];
    const float* fw   = (const float*)d_in[29];
    const float* fb   = (const float*)d_in[30];

    const int N = NNODES;
    float* out = (float*)d_out;                    // [N,128]
    float* x3  = out + (size_t)N * 128;            // [N,128]
    float* pf  = out + (size_t)2 * N * 128;        // [N,128]

    char* ws = (char*)d_ws;
    size_t off = 0;
    auto alloc = [&](size_t bytes) -> void* {
        void* p = ws + off;
        off += (bytes + 255) / 256 * 256;
        return p;
    };
    int*   cnt    = (int*)alloc((size_t)(N + 1) * 4);      // per-node degree + spill count
    int*   srcs   = (int*)alloc((size_t)N * ELLW * 4);
    int2*  ovbuf  = (int2*)alloc((size_t)NETOT * 8);
    float* esb    = (float*)alloc((size_t)N * 4 * 4);
    float* edb    = (float*)alloc((size_t)N * 4 * 4);
    u16*   w1c    = (u16*)alloc(16384 * 2);
    u16*   w2c    = (u16*)alloc(32768 * 2);
    u16*   w3c    = (u16*)alloc(16384 * 2);
    u16*   pw2c   = (u16*)alloc(8192 * 2);
    u16*   pw3c   = (u16*)alloc(16384 * 2);
    u16*   fwc    = (u16*)alloc(32768 * 2);
    u16*   hbufb  = (u16*)alloc((size_t)N * 256 * 2);
    u16*   xb     = (u16*)alloc((size_t)N * 256 * 2);
    u16*   p2b    = (u16*)alloc((size_t)N * 128 * 2);

    // ---- ELL build (1 memset + 1 kernel) ----
    hipMemsetAsync(cnt, 0, (size_t)(N + 1) * 4, stream);
    ell_scatter_kernel<<<(NETOT + 255) / 256, 256, 0, stream>>>(ei, cnt, srcs, ovbuf);

    // ---- weights-only cast (counts = float4 groups) ----
    castw_kernel<<<(30720 + 255) / 256, 256, 0, stream>>>(
        W1, w1c, 4096, W2, w2c, 8192, W3, w3c, 4096,
        pw2, pw2c, 2048, pw3, pw3c, 4096, fw, fwc, 8192);

    const int NW = N / 4;   // one-wave-per-node kernels: 256 thr = 4 waves
    const int GB = N / 64;  // 625 GEMM row-blocks

    // ---- PointNet layers 1+2 (fused) ----
    gemm_pn12_kernel<<<GB, 256, 0, stream>>>(
        pos, pw1, pb1, bn1g, bn1b, pw2c, p2b, pb2, bn2g, bn2b, N);

    // ---- GAT layer 1 ----
    gemm_scores_kernel<4, 64, true><<<dim3(GB, 2), 256, 0, stream>>>(
        x, w1c, hbufb, as1, ad1, esb, edb, N, 256, 64);
    gat_fused_kernel<4, 64, true><<<NW, 256, 0, stream>>>(
        hbufb, esb, edb, cnt, srcs, ovbuf, bg1, ln1g, ln1b, xb, N);

    // ---- GAT layer 2 ----
    gemm_scores_kernel<2, 64, false><<<dim3(GB, 1), 256, 0, stream>>>(
        xb, w2c, hbufb, as2, ad2, esb, edb, N, 128, 256);
    gat_fused_kernel<2, 64, true><<<NW, 256, 0, stream>>>(
        hbufb, esb, edb, cnt, srcs, ovbuf, bg2, ln2g, ln2b, xb, N);

    // ---- GAT layer 3 (out f32 -> x3) ----
    gemm_scores_kernel<1, 128, false><<<dim3(GB, 1), 256, 0, stream>>>(
        xb, w3c, hbufb, as3, ad3, esb, edb, N, 128, 128);
    gat_fused_kernel<1, 128, false><<<NW, 256, 0, stream>>>(
        hbufb, esb, edb, cnt, srcs, ovbuf, bg3, nullptr, nullptr, x3, N);

    // ---- pw3 GEMM + fusion GEMM (fused; writes pf and out) ----
    gemm_pw3cat_kernel<<<GB, 256, 0, stream>>>(p2b, pw3c, pb3, pf, x3, fwc, fb, out, N);
}